// Round 1
// baseline (519.370 us; speedup 1.0000x reference)
//
#include <hip/hip_runtime.h>
#include <hip/hip_bf16.h>
#include <math.h>

typedef short v8s __attribute__((ext_vector_type(8)));
typedef float v4f __attribute__((ext_vector_type(4)));

#define L_SEQ 1024
#define D_SINGLE 384
#define N_HEADS 12
#define HEAD_DIM 32
#define D_PAIR 128

static __device__ inline short f2bf(float f) {
    __hip_bfloat16 h = __float2bfloat16(f);
    return *reinterpret_cast<short*>(&h);
}

static __device__ inline float gelu_exact(float x) {
    return 0.5f * x * (1.0f + erff(x * 0.70710678118654752f));
}

// ---------------- LayerNorm: 4 rows per block, 1 wave per row ----------------
__global__ __launch_bounds__(256) void ln_k(const float* __restrict__ x,
                                            const float* __restrict__ g,
                                            const float* __restrict__ b,
                                            float* __restrict__ y,
                                            float* __restrict__ pre,
                                            const float* __restrict__ pre_bias) {
    const int wid = threadIdx.x >> 6, lane = threadIdx.x & 63;
    const int row = blockIdx.x * 4 + wid;
    const float* xr = x + (long)row * D_SINGLE;
    float v[6];
    float s = 0.f;
#pragma unroll
    for (int t = 0; t < 6; ++t) { v[t] = xr[lane + t * 64]; s += v[t]; }
#pragma unroll
    for (int o = 32; o >= 1; o >>= 1) s += __shfl_xor(s, o);
    const float mean = s * (1.f / D_SINGLE);
    float q = 0.f;
#pragma unroll
    for (int t = 0; t < 6; ++t) { float d = v[t] - mean; q += d * d; }
#pragma unroll
    for (int o = 32; o >= 1; o >>= 1) q += __shfl_xor(q, o);
    const float rs = rsqrtf(q * (1.f / D_SINGLE) + 1e-5f);
    float* yr = y + (long)row * D_SINGLE;
#pragma unroll
    for (int t = 0; t < 6; ++t) {
        int c = lane + t * 64;
        yr[c] = (v[t] - mean) * rs * g[c] + b[c];
        if (pre) pre[(long)row * D_SINGLE + c] = v[t] + pre_bias[c];
    }
}

// ---------------- pair bias via MFMA 16x16x32 bf16 ----------------
__global__ __launch_bounds__(256) void pairb_k(const float* __restrict__ pair,
                                               const float* __restrict__ Wb,
                                               float* __restrict__ logits) {
    const int lane = threadIdx.x & 63;
    const int wid = threadIdx.x >> 6;
    const int c = lane & 15;   // A row / C col
    const int g = lane >> 4;   // k-group 0..3
    const long cellbase = ((long)blockIdx.x * 4 + wid) * 16;

    v8s bfrag[4];
#pragma unroll
    for (int t = 0; t < 4; ++t) {
#pragma unroll
        for (int j = 0; j < 8; ++j) {
            int p = t * 32 + g * 8 + j;
            float w = (c < N_HEADS) ? Wb[p * N_HEADS + c] : 0.f;
            bfrag[t][j] = f2bf(w);
        }
    }

    const float* src = pair + (cellbase + c) * (long)D_PAIR + g * 8;
    float4 x0[4], x1[4];
#pragma unroll
    for (int t = 0; t < 4; ++t) {
        x0[t] = *reinterpret_cast<const float4*>(src + 32 * t);
        x1[t] = *reinterpret_cast<const float4*>(src + 32 * t + 4);
    }
    v4f acc = {0.f, 0.f, 0.f, 0.f};
#pragma unroll
    for (int t = 0; t < 4; ++t) {
        v8s a;
        a[0] = f2bf(x0[t].x); a[1] = f2bf(x0[t].y); a[2] = f2bf(x0[t].z); a[3] = f2bf(x0[t].w);
        a[4] = f2bf(x1[t].x); a[5] = f2bf(x1[t].y); a[6] = f2bf(x1[t].z); a[7] = f2bf(x1[t].w);
        acc = __builtin_amdgcn_mfma_f32_16x16x32_bf16(a, bfrag[t], acc, 0, 0, 0);
    }
    if (c < N_HEADS) {
        float4 o; o.x = acc[0]; o.y = acc[1]; o.z = acc[2]; o.w = acc[3];
        *reinterpret_cast<float4*>(logits + (long)c * 1048576 + cellbase + g * 4) = o;
    }
}

// ---------------- generic fp32 tiled GEMM ----------------
template <int BM, int BN, int BK, int TM, int TN>
__global__ __launch_bounds__(256) void gemm_k(const float* __restrict__ A, int lda, long Az,
                                              const float* __restrict__ B, int ldb, long Bz,
                                              float* __restrict__ C, int ldc, long Cz,
                                              int K,
                                              const float* __restrict__ bias,
                                              const float* __restrict__ res, int resmode,
                                              int act, float alpha, int smode, int ksplit) {
    const int z = blockIdx.z;
    int kbeg = 0, kend = K;
    if (ksplit > 1) {
        int kc = K / ksplit; kbeg = z * kc; kend = kbeg + kc;
    } else {
        A += (long)z * Az; B += (long)z * Bz; C += (long)z * Cz;
    }
    const int m0 = blockIdx.x * BM, n0 = blockIdx.y * BN;
    __shared__ float AsT[BK][BM + 4];
    __shared__ float Bs[BK][BN];
    constexpr int TXN = BN / TN;
    const int tid = threadIdx.x;
    const int tx = tid % TXN, ty = tid / TXN;

    float acc[TM][TN];
#pragma unroll
    for (int i = 0; i < TM; ++i)
#pragma unroll
        for (int j = 0; j < TN; ++j) acc[i][j] = 0.f;

    for (int k0 = kbeg; k0 < kend; k0 += BK) {
        constexpr int NA = BM * BK / 4;
        constexpr int NB = BK * BN / 4;
        for (int i = tid; i < NA; i += 256) {
            int r = i / (BK / 4), c4 = (i % (BK / 4)) * 4;
            float4 av = *reinterpret_cast<const float4*>(A + (long)(m0 + r) * lda + k0 + c4);
            AsT[c4 + 0][r] = av.x; AsT[c4 + 1][r] = av.y;
            AsT[c4 + 2][r] = av.z; AsT[c4 + 3][r] = av.w;
        }
        for (int i = tid; i < NB; i += 256) {
            int r = i / (BN / 4), c4 = (i % (BN / 4)) * 4;
            *reinterpret_cast<float4*>(&Bs[r][c4]) =
                *reinterpret_cast<const float4*>(B + (long)(k0 + r) * ldb + n0 + c4);
        }
        __syncthreads();
#pragma unroll
        for (int kk = 0; kk < BK; ++kk) {
            float a[TM], b[TN];
#pragma unroll
            for (int i = 0; i < TM; ++i) a[i] = AsT[kk][ty * TM + i];
#pragma unroll
            for (int j = 0; j < TN; ++j) b[j] = Bs[kk][tx * TN + j];
#pragma unroll
            for (int i = 0; i < TM; ++i)
#pragma unroll
                for (int j = 0; j < TN; ++j) acc[i][j] = fmaf(a[i], b[j], acc[i][j]);
        }
        __syncthreads();
    }

#pragma unroll
    for (int i = 0; i < TM; ++i) {
#pragma unroll
        for (int j = 0; j < TN; ++j) {
            int grow = m0 + ty * TM + i, gcol = n0 + tx * TN + j;
            float v = alpha * acc[i][j];
            if (bias) v += bias[gcol];
            if (resmode == 1) v += res[(long)grow * ldc + gcol];
            else if (resmode == 2) v += C[(long)grow * ldc + gcol];
            if (act == 1) v = gelu_exact(v);
            if (smode == 0) C[(long)grow * ldc + gcol] = v;
            else if (smode == 1) {
                int h = gcol >> 5, d = gcol & 31;
                C[(long)h * 32768 + (long)d * 1024 + grow] = v;
            } else {
                atomicAdd(&C[(long)grow * ldc + gcol], v);
            }
        }
    }
}

// ---------------- row softmax in-place over 1024 cols ----------------
__global__ __launch_bounds__(256) void softmax_k(float* __restrict__ w) {
    __shared__ float redm[4];
    __shared__ float reds[4];
    const int tid = threadIdx.x, lane = tid & 63, wid = tid >> 6;
    float* row = w + (long)blockIdx.x * 1024;
    float4 x = *reinterpret_cast<float4*>(row + tid * 4);
    float m = fmaxf(fmaxf(x.x, x.y), fmaxf(x.z, x.w));
#pragma unroll
    for (int o = 32; o >= 1; o >>= 1) m = fmaxf(m, __shfl_xor(m, o));
    if (lane == 0) redm[wid] = m;
    __syncthreads();
    m = fmaxf(fmaxf(redm[0], redm[1]), fmaxf(redm[2], redm[3]));
    x.x = __expf(x.x - m); x.y = __expf(x.y - m);
    x.z = __expf(x.z - m); x.w = __expf(x.w - m);
    float s = x.x + x.y + x.z + x.w;
#pragma unroll
    for (int o = 32; o >= 1; o >>= 1) s += __shfl_xor(s, o);
    if (lane == 0) reds[wid] = s;
    __syncthreads();
    s = reds[0] + reds[1] + reds[2] + reds[3];
    float inv = 1.f / s;
    x.x *= inv; x.y *= inv; x.z *= inv; x.w *= inv;
    *reinterpret_cast<float4*>(row + tid * 4) = x;
}

extern "C" void kernel_launch(void* const* d_in, const int* in_sizes, int n_in,
                              void* d_out, int out_size, void* d_ws, size_t ws_size,
                              hipStream_t stream) {
    const float* s    = (const float*)d_in[0];
    const float* pair = (const float*)d_in[1];
    const float* g_s = (const float*)d_in[3];
    const float* b_s = (const float*)d_in[4];
    const float* Wq  = (const float*)d_in[5];
    const float* Wk  = (const float*)d_in[6];
    const float* Wv  = (const float*)d_in[7];
    const float* Wb  = (const float*)d_in[8];
    const float* Wo  = (const float*)d_in[9];
    const float* bo  = (const float*)d_in[10];
    const float* g_f = (const float*)d_in[11];
    const float* b_f = (const float*)d_in[12];
    const float* W1  = (const float*)d_in[13];
    const float* b1  = (const float*)d_in[14];
    const float* W2  = (const float*)d_in[15];
    const float* b2  = (const float*)d_in[16];
    float* out = (float*)d_out;

    float* ws = (float*)d_ws;
    const long NSD = (long)L_SEQ * D_SINGLE;
    float* sn  = ws;
    float* qb  = ws + NSD;
    float* kT  = ws + 2 * NSD;
    float* vb  = ws + 3 * NSD;
    float* att = ws + 4 * NSD;
    float* s1  = ws + 5 * NSD;
    float* hn  = ws + 6 * NSD;
    float* t1  = ws + 7 * NSD;
    float* lg  = ws + 7 * NSD + (long)L_SEQ * 1536;

    const dim3 blk(256);
    const float scale = 0.17677669529663688f;

    ln_k<<<dim3(256), blk, 0, stream>>>(s, g_s, b_s, sn, nullptr, nullptr);

    gemm_k<64, 64, 16, 4, 4><<<dim3(16, 6, 1), blk, 0, stream>>>(
        sn, 384, 0, Wq, 384, 0, qb, 384, 0, 384, nullptr, nullptr, 0, 0, 1.f, 0, 1);
    gemm_k<64, 64, 16, 4, 4><<<dim3(16, 6, 1), blk, 0, stream>>>(
        sn, 384, 0, Wk, 384, 0, kT, 384, 0, 384, nullptr, nullptr, 0, 0, 1.f, 1, 1);
    gemm_k<64, 64, 16, 4, 4><<<dim3(16, 6, 1), blk, 0, stream>>>(
        sn, 384, 0, Wv, 384, 0, vb, 384, 0, 384, nullptr, nullptr, 0, 0, 1.f, 0, 1);

    pairb_k<<<dim3(16384), blk, 0, stream>>>(pair, Wb, lg);

    gemm_k<64, 64, 16, 4, 4><<<dim3(16, 16, 12), blk, 0, stream>>>(
        qb, 384, 32, kT, 1024, 32768, lg, 1024, 1048576, 32,
        nullptr, nullptr, 2, 0, scale, 0, 1);

    softmax_k<<<dim3(12288), blk, 0, stream>>>(lg);

    gemm_k<64, 32, 16, 4, 2><<<dim3(16, 1, 12), blk, 0, stream>>>(
        lg, 1024, 1048576, vb, 384, 32, att, 384, 32, 1024,
        nullptr, nullptr, 0, 0, 1.f, 0, 1);

    gemm_k<32, 64, 16, 2, 4><<<dim3(32, 6, 1), blk, 0, stream>>>(
        att, 384, 0, Wo, 384, 0, s1, 384, 0, 384, bo, s, 1, 0, 1.f, 0, 1);

    ln_k<<<dim3(256), blk, 0, stream>>>(s1, g_f, b_f, hn, out, b2);

    gemm_k<64, 64, 16, 4, 4><<<dim3(16, 24, 1), blk, 0, stream>>>(
        hn, 384, 0, W1, 1536, 0, t1, 1536, 0, 384, b1, nullptr, 0, 1, 1.f, 0, 1);

    gemm_k<32, 64, 16, 2, 4><<<dim3(32, 6, 4), blk, 0, stream>>>(
        t1, 1536, 0, W2, 384, 0, out, 384, 0, 1536,
        nullptr, nullptr, 0, 0, 1.f, 2, 4);
}

// Round 2
// 308.709 us; speedup vs baseline: 1.6824x; 1.6824x over previous
//
#include <hip/hip_runtime.h>
#include <hip/hip_bf16.h>
#include <math.h>

typedef short v8s __attribute__((ext_vector_type(8)));
typedef float v4f __attribute__((ext_vector_type(4)));

#define LSEQ 1024
#define DS 384
#define NH 12
#define HD 32
#define DP 128

static __device__ inline ushort f2bf(float f) {
    __hip_bfloat16 h = __float2bfloat16(f);
    return *reinterpret_cast<ushort*>(&h);
}
static __device__ inline float gelu_exact(float x) {
    return 0.5f * x * (1.0f + erff(x * 0.70710678118654752f));
}

// ---------- LayerNorm: 4 rows/block, 1 wave/row; bf16 main out, optional f32 prefill ----------
__global__ __launch_bounds__(256) void ln_k(const float* __restrict__ x,
                                            const float* __restrict__ g,
                                            const float* __restrict__ b,
                                            ushort* __restrict__ ybf,
                                            float* __restrict__ pre,
                                            const float* __restrict__ pre_bias) {
    const int wid = threadIdx.x >> 6, lane = threadIdx.x & 63;
    const int row = blockIdx.x * 4 + wid;
    const float* xr = x + (long)row * DS;
    float v[6];
    float s = 0.f;
#pragma unroll
    for (int t = 0; t < 6; ++t) { v[t] = xr[lane + t * 64]; s += v[t]; }
#pragma unroll
    for (int o = 32; o >= 1; o >>= 1) s += __shfl_xor(s, o);
    const float mean = s * (1.f / DS);
    float q = 0.f;
#pragma unroll
    for (int t = 0; t < 6; ++t) { float d = v[t] - mean; q += d * d; }
#pragma unroll
    for (int o = 32; o >= 1; o >>= 1) q += __shfl_xor(q, o);
    const float rs = rsqrtf(q * (1.f / DS) + 1e-5f);
#pragma unroll
    for (int t = 0; t < 6; ++t) {
        int c = lane + t * 64;
        ybf[(long)row * DS + c] = f2bf((v[t] - mean) * rs * g[c] + b[c]);
        if (pre) pre[(long)row * DS + c] = v[t] + pre_bias[c];
    }
}

// ---------- weight transpose + convert: W[K][N] f32 -> WT[N][K] bf16 ----------
__global__ __launch_bounds__(256) void wcvt_k(const float* __restrict__ W,
                                              ushort* __restrict__ WT, int Kd, int Nd) {
    __shared__ float tile[32][33];
    const int k0 = blockIdx.x * 32, n0 = blockIdx.y * 32;
    const int t = threadIdx.x;
    const int r = t >> 3, c4 = (t & 7) * 4;
    float4 v = *reinterpret_cast<const float4*>(W + (long)(k0 + r) * Nd + n0 + c4);
    tile[r][c4 + 0] = v.x; tile[r][c4 + 1] = v.y;
    tile[r][c4 + 2] = v.z; tile[r][c4 + 3] = v.w;
    __syncthreads();
    ushort4 o;
    o.x = f2bf(tile[c4 + 0][r]); o.y = f2bf(tile[c4 + 1][r]);
    o.z = f2bf(tile[c4 + 2][r]); o.w = f2bf(tile[c4 + 3][r]);
    *reinterpret_cast<ushort4*>(WT + (long)(n0 + r) * Kd + k0 + c4) = o;
}

// ---------- pair bias via MFMA 16x16x32 bf16 (validated layout) ----------
__global__ __launch_bounds__(256) void pairb_k(const float* __restrict__ pair,
                                               const float* __restrict__ Wb,
                                               float* __restrict__ logits) {
    const int lane = threadIdx.x & 63;
    const int wid = threadIdx.x >> 6;
    const int c = lane & 15;
    const int g = lane >> 4;
    const long cellbase = ((long)blockIdx.x * 4 + wid) * 16;

    v8s bfrag[4];
#pragma unroll
    for (int t = 0; t < 4; ++t) {
#pragma unroll
        for (int j = 0; j < 8; ++j) {
            int p = t * 32 + g * 8 + j;
            float w = (c < NH) ? Wb[p * NH + c] : 0.f;
            bfrag[t][j] = (short)f2bf(w);
        }
    }
    const float* src = pair + (cellbase + c) * (long)DP + g * 8;
    float4 x0[4], x1[4];
#pragma unroll
    for (int t = 0; t < 4; ++t) {
        x0[t] = *reinterpret_cast<const float4*>(src + 32 * t);
        x1[t] = *reinterpret_cast<const float4*>(src + 32 * t + 4);
    }
    v4f acc = {0.f, 0.f, 0.f, 0.f};
#pragma unroll
    for (int t = 0; t < 4; ++t) {
        v8s a;
        a[0] = (short)f2bf(x0[t].x); a[1] = (short)f2bf(x0[t].y);
        a[2] = (short)f2bf(x0[t].z); a[3] = (short)f2bf(x0[t].w);
        a[4] = (short)f2bf(x1[t].x); a[5] = (short)f2bf(x1[t].y);
        a[6] = (short)f2bf(x1[t].z); a[7] = (short)f2bf(x1[t].w);
        acc = __builtin_amdgcn_mfma_f32_16x16x32_bf16(a, bfrag[t], acc, 0, 0, 0);
    }
    if (c < NH) {
        float4 o; o.x = acc[0]; o.y = acc[1]; o.z = acc[2]; o.w = acc[3];
        *reinterpret_cast<float4*>(logits + (long)c * 1048576 + cellbase + g * 4) = o;
    }
}

// ---------- register-resident bf16 MFMA GEMM: C[M][N] = A[M][K] @ BT[N][K]^T ----------
// block 256 = 4 waves as 2x2; wave tile 32x32; no LDS (A/BT are L2-resident bf16).
// EPI: 0 f32 store; 1 f32 store + res; 2 f32 +=; 3 bf16 gelu store; 4 bf16 store
template <int EPI>
__global__ __launch_bounds__(256) void mgemm_k(const ushort* __restrict__ A,
                                               const ushort* __restrict__ BT,
                                               float* __restrict__ Cf,
                                               ushort* __restrict__ Cb,
                                               const float* __restrict__ bias,
                                               const float* __restrict__ res,
                                               int K, int ldc) {
    const int w = threadIdx.x >> 6;
    const int lane = threadIdx.x & 63;
    const int c = lane & 15, g = lane >> 4;
    const int m0 = blockIdx.x * 64 + (w >> 1) * 32;
    const int n0 = blockIdx.y * 64 + (w & 1) * 32;

    v4f acc[2][2];
#pragma unroll
    for (int i = 0; i < 2; ++i)
#pragma unroll
        for (int j = 0; j < 2; ++j) acc[i][j] = (v4f){0.f, 0.f, 0.f, 0.f};

    const ushort* Ap0 = A + (long)(m0 + c) * K + g * 8;
    const ushort* Ap1 = A + (long)(m0 + 16 + c) * K + g * 8;
    const ushort* Bp0 = BT + (long)(n0 + c) * K + g * 8;
    const ushort* Bp1 = BT + (long)(n0 + 16 + c) * K + g * 8;

#pragma unroll 2
    for (int k0 = 0; k0 < K; k0 += 32) {
        v8s a0 = *reinterpret_cast<const v8s*>(Ap0 + k0);
        v8s a1 = *reinterpret_cast<const v8s*>(Ap1 + k0);
        v8s b0 = *reinterpret_cast<const v8s*>(Bp0 + k0);
        v8s b1 = *reinterpret_cast<const v8s*>(Bp1 + k0);
        acc[0][0] = __builtin_amdgcn_mfma_f32_16x16x32_bf16(a0, b0, acc[0][0], 0, 0, 0);
        acc[0][1] = __builtin_amdgcn_mfma_f32_16x16x32_bf16(a0, b1, acc[0][1], 0, 0, 0);
        acc[1][0] = __builtin_amdgcn_mfma_f32_16x16x32_bf16(a1, b0, acc[1][0], 0, 0, 0);
        acc[1][1] = __builtin_amdgcn_mfma_f32_16x16x32_bf16(a1, b1, acc[1][1], 0, 0, 0);
    }

#pragma unroll
    for (int mi = 0; mi < 2; ++mi) {
#pragma unroll
        for (int ni = 0; ni < 2; ++ni) {
#pragma unroll
            for (int r = 0; r < 4; ++r) {
                const int row = m0 + mi * 16 + g * 4 + r;
                const int col = n0 + ni * 16 + c;
                float v = acc[mi][ni][r];
                if (bias) v += bias[col];
                const long idx = (long)row * ldc + col;
                if (EPI == 0) Cf[idx] = v;
                else if (EPI == 1) Cf[idx] = v + res[idx];
                else if (EPI == 2) Cf[idx] += v;
                else if (EPI == 3) Cb[idx] = f2bf(gelu_exact(v));
                else Cb[idx] = f2bf(v);
            }
        }
    }
}

// ---------- fused flash attention over precomputed pair-bias ----------
// block = (head, 64 q-rows), 4 waves x 16 rows. qkv bf16 [1024][1152] (q|k|v each 384).
// S = scale*(q@k^T) + lg[h];  online softmax;  O = P@V;  att bf16 [1024][384].
__global__ __launch_bounds__(256) void flash_k(const ushort* __restrict__ qkv,
                                               const float* __restrict__ lg,
                                               ushort* __restrict__ att) {
    const int h = blockIdx.y;
    const int q0 = blockIdx.x * 64;
    const int w = threadIdx.x >> 6;
    const int lane = threadIdx.x & 63;
    const int c = lane & 15, g = lane >> 4;
    const float scale = 0.17677669529663688f;

    __shared__ ushort VT[32][80];      // V^T per k-tile: [d][k], padded (4-way max)
    __shared__ ushort P[4][16][80];    // per-wave P tile [row][k], padded

    // hoisted Q fragment for this wave's 16 rows
    const v8s aq = *reinterpret_cast<const v8s*>(
        qkv + (long)(q0 + w * 16 + c) * 1152 + h * 32 + g * 8);

    v4f acc0 = {0.f, 0.f, 0.f, 0.f};   // O cols d = c
    v4f acc1 = {0.f, 0.f, 0.f, 0.f};   // O cols d = c + 16
    float m_run[4], l_run[4];
#pragma unroll
    for (int r = 0; r < 4; ++r) { m_run[r] = -INFINITY; l_run[r] = 0.f; }

    for (int kt = 0; kt < 16; ++kt) {
        const int k0 = kt * 64;
        __syncthreads();   // previous tile's VT fully consumed
        {   // stage V^T : read v rows coalesced, scatter-transpose to LDS
            const int kk = threadIdx.x >> 2;        // 0..63
            const int c4 = threadIdx.x & 3;         // 0..3
            v8s vv = *reinterpret_cast<const v8s*>(
                qkv + (long)(k0 + kk) * 1152 + 768 + h * 32 + c4 * 8);
#pragma unroll
            for (int j = 0; j < 8; ++j) VT[c4 * 8 + j][kk] = (ushort)vv[j];
        }
        __syncthreads();

        // ---- QK^T: 4 MFMA (K=32 in one step each), n-subtiles of 16 keys ----
        v4f sfr[4];
#pragma unroll
        for (int nf = 0; nf < 4; ++nf) {
            v8s bk = *reinterpret_cast<const v8s*>(
                qkv + (long)(k0 + nf * 16 + c) * 1152 + 384 + h * 32 + g * 8);
            v4f z = {0.f, 0.f, 0.f, 0.f};
            sfr[nf] = __builtin_amdgcn_mfma_f32_16x16x32_bf16(aq, bk, z, 0, 0, 0);
        }

        // ---- bias + scale, row max ----
        float p[4][4];
        float mx[4];
#pragma unroll
        for (int r = 0; r < 4; ++r) mx[r] = -INFINITY;
        const float* lgb = lg + (long)h * 1048576 + (long)(q0 + w * 16 + g * 4) * 1024 + k0;
#pragma unroll
        for (int nf = 0; nf < 4; ++nf) {
#pragma unroll
            for (int r = 0; r < 4; ++r) {
                float bias = lgb[(long)r * 1024 + nf * 16 + c];
                float sv = sfr[nf][r] * scale + bias;
                p[nf][r] = sv;
                mx[r] = fmaxf(mx[r], sv);
            }
        }
#pragma unroll
        for (int r = 0; r < 4; ++r) {
            mx[r] = fmaxf(mx[r], __shfl_xor(mx[r], 1));
            mx[r] = fmaxf(mx[r], __shfl_xor(mx[r], 2));
            mx[r] = fmaxf(mx[r], __shfl_xor(mx[r], 4));
            mx[r] = fmaxf(mx[r], __shfl_xor(mx[r], 8));
        }

        // ---- online update: exp, rescale O, accumulate l ----
        float ts[4];
#pragma unroll
        for (int r = 0; r < 4; ++r) {
            const float mnew = fmaxf(m_run[r], mx[r]);
            const float ef = __expf(m_run[r] - mnew);   // 0 on first tile
            m_run[r] = mnew;
            float t = 0.f;
#pragma unroll
            for (int nf = 0; nf < 4; ++nf) {
                p[nf][r] = __expf(p[nf][r] - mnew);
                t += p[nf][r];
            }
            ts[r] = t;
            acc0[r] *= ef; acc1[r] *= ef;
            l_run[r] *= ef;
        }
#pragma unroll
        for (int r = 0; r < 4; ++r) {
            ts[r] += __shfl_xor(ts[r], 1);
            ts[r] += __shfl_xor(ts[r], 2);
            ts[r] += __shfl_xor(ts[r], 4);
            ts[r] += __shfl_xor(ts[r], 8);
            l_run[r] += ts[r];
        }

        // ---- P -> LDS (bf16), rows g*4+r, cols nf*16+c ----
#pragma unroll
        for (int nf = 0; nf < 4; ++nf)
#pragma unroll
            for (int r = 0; r < 4; ++r)
                P[w][g * 4 + r][nf * 16 + c] = f2bf(p[nf][r]);

        // ---- PV: A = P (m=row), B = VT (n=d); K=64 as 2 steps ----
        v8s pa0 = *reinterpret_cast<const v8s*>(&P[w][c][g * 8]);
        v8s pa1 = *reinterpret_cast<const v8s*>(&P[w][c][32 + g * 8]);
        v8s v00 = *reinterpret_cast<const v8s*>(&VT[c][g * 8]);
        v8s v01 = *reinterpret_cast<const v8s*>(&VT[c][32 + g * 8]);
        v8s v10 = *reinterpret_cast<const v8s*>(&VT[c + 16][g * 8]);
        v8s v11 = *reinterpret_cast<const v8s*>(&VT[c + 16][32 + g * 8]);
        acc0 = __builtin_amdgcn_mfma_f32_16x16x32_bf16(pa0, v00, acc0, 0, 0, 0);
        acc0 = __builtin_amdgcn_mfma_f32_16x16x32_bf16(pa1, v01, acc0, 0, 0, 0);
        acc1 = __builtin_amdgcn_mfma_f32_16x16x32_bf16(pa0, v10, acc1, 0, 0, 0);
        acc1 = __builtin_amdgcn_mfma_f32_16x16x32_bf16(pa1, v11, acc1, 0, 0, 0);
    }

    // ---- finalize ----
#pragma unroll
    for (int r = 0; r < 4; ++r) {
        const float inv = 1.f / l_run[r];
        const long row = q0 + w * 16 + g * 4 + r;
        att[row * DS + h * 32 + c] = f2bf(acc0[r] * inv);
        att[row * DS + h * 32 + 16 + c] = f2bf(acc1[r] * inv);
    }
}

extern "C" void kernel_launch(void* const* d_in, const int* in_sizes, int n_in,
                              void* d_out, int out_size, void* d_ws, size_t ws_size,
                              hipStream_t stream) {
    const float* s    = (const float*)d_in[0];
    const float* pair = (const float*)d_in[1];
    const float* g_s = (const float*)d_in[3];
    const float* b_s = (const float*)d_in[4];
    const float* Wq  = (const float*)d_in[5];
    const float* Wk  = (const float*)d_in[6];
    const float* Wv  = (const float*)d_in[7];
    const float* Wb  = (const float*)d_in[8];
    const float* Wo  = (const float*)d_in[9];
    const float* bo  = (const float*)d_in[10];
    const float* g_f = (const float*)d_in[11];
    const float* b_f = (const float*)d_in[12];
    const float* W1  = (const float*)d_in[13];
    const float* b1  = (const float*)d_in[14];
    const float* W2  = (const float*)d_in[15];
    const float* b2  = (const float*)d_in[16];
    float* out = (float*)d_out;

    char* ws = (char*)d_ws;
    float*  lg   = (float*)ws;                          ws += 50331648;  // 12*1024*1024*4
    float*  s1   = (float*)ws;                          ws += 1572864;   // 1024*384*4
    ushort* qkv  = (ushort*)ws;                         ws += 2359296;   // 1024*1152*2
    ushort* sn   = (ushort*)ws;                         ws += 786432;
    ushort* hn   = (ushort*)ws;                         ws += 786432;
    ushort* attb = (ushort*)ws;                         ws += 786432;
    ushort* t1   = (ushort*)ws;                         ws += 3145728;   // 1024*1536*2
    ushort* qkvT = (ushort*)ws;                         ws += 884736;    // 1152*384*2
    ushort* WoT  = (ushort*)ws;                         ws += 294912;
    ushort* W1T  = (ushort*)ws;                         ws += 1179648;   // 1536*384*2
    ushort* W2T  = (ushort*)ws;                         ws += 1179648;   // 384*1536*2

    const dim3 blk(256);

    // weight transposes/conversions (f32 -> bf16 [N][K])
    wcvt_k<<<dim3(12, 12), blk, 0, stream>>>(Wq, qkvT,             384, 384);
    wcvt_k<<<dim3(12, 12), blk, 0, stream>>>(Wk, qkvT + 384 * 384, 384, 384);
    wcvt_k<<<dim3(12, 12), blk, 0, stream>>>(Wv, qkvT + 768 * 384, 384, 384);
    wcvt_k<<<dim3(12, 12), blk, 0, stream>>>(Wo, WoT,              384, 384);
    wcvt_k<<<dim3(12, 48), blk, 0, stream>>>(W1, W1T,              384, 1536);
    wcvt_k<<<dim3(48, 12), blk, 0, stream>>>(W2, W2T,              1536, 384);

    // pair bias -> lg (the big 512 MB read)
    pairb_k<<<dim3(16384), blk, 0, stream>>>(pair, Wb, lg);

    // LN1 -> sn (bf16)
    ln_k<<<dim3(256), blk, 0, stream>>>(s, g_s, b_s, sn, nullptr, nullptr);

    // QKV: qkv[1024][1152] bf16
    mgemm_k<4><<<dim3(16, 18), blk, 0, stream>>>(sn, qkvT, nullptr, qkv,
                                                 nullptr, nullptr, 384, 1152);

    // fused attention
    flash_k<<<dim3(16, 12), blk, 0, stream>>>(qkv, lg, attb);

    // s1 = att @ Wo + bo + s
    mgemm_k<1><<<dim3(16, 6), blk, 0, stream>>>(attb, WoT, s1, nullptr,
                                                bo, s, 384, 384);

    // LN2 -> hn (bf16), prefill out = s1 + b2
    ln_k<<<dim3(256), blk, 0, stream>>>(s1, g_f, b_f, hn, out, b2);

    // t1 = gelu(hn @ W1 + b1) (bf16)
    mgemm_k<3><<<dim3(16, 24), blk, 0, stream>>>(hn, W1T, nullptr, t1,
                                                 b1, nullptr, 384, 1536);

    // out += t1 @ W2
    mgemm_k<2><<<dim3(16, 6), blk, 0, stream>>>(t1, W2T, out, nullptr,
                                                nullptr, nullptr, 1536, 384);
}

// Round 3
// 270.796 us; speedup vs baseline: 1.9179x; 1.1400x over previous
//
#include <hip/hip_runtime.h>
#include <hip/hip_bf16.h>
#include <math.h>

typedef short v8s __attribute__((ext_vector_type(8)));
typedef float v4f __attribute__((ext_vector_type(4)));

#define LSEQ 1024
#define DS 384
#define NH 12
#define HD 32
#define DP 128

static __device__ inline ushort f2bf(float f) {
    __hip_bfloat16 h = __float2bfloat16(f);
    return *reinterpret_cast<ushort*>(&h);
}
static __device__ inline float bf2f(ushort u) {
    return __uint_as_float(((unsigned int)u) << 16);
}
static __device__ inline float gelu_exact(float x) {
    return 0.5f * x * (1.0f + erff(x * 0.70710678118654752f));
}

// ==================== fused prep: pairb (16384) + wcvt (1728) + ln1 (256) ====================
// block ranges: [0,16384) pairb ; [16384,18112) weight cvt ; [18112,18368) LN1
__global__ __launch_bounds__(256) void prep_k(const float* __restrict__ pair,
                                              const float* __restrict__ Wb,
                                              ushort* __restrict__ lg,
                                              const float* __restrict__ s,
                                              const float* __restrict__ g_s,
                                              const float* __restrict__ b_s,
                                              ushort* __restrict__ sn,
                                              const float* __restrict__ Wq,
                                              const float* __restrict__ Wk,
                                              const float* __restrict__ Wv,
                                              const float* __restrict__ Wo,
                                              const float* __restrict__ W1,
                                              const float* __restrict__ W2,
                                              ushort* __restrict__ qkvT,
                                              ushort* __restrict__ WoT,
                                              ushort* __restrict__ W1T,
                                              ushort* __restrict__ W2T) {
    __shared__ float tile[32][33];
    const int bid = blockIdx.x;
    const int tid = threadIdx.x;

    if (bid < 16384) {
        // ---------------- pair bias via MFMA 16x16x32 bf16 ----------------
        const int lane = tid & 63;
        const int wid = tid >> 6;
        const int c = lane & 15;
        const int g = lane >> 4;
        const long cellbase = ((long)bid * 4 + wid) * 16;

        v8s bfrag[4];
#pragma unroll
        for (int t = 0; t < 4; ++t) {
#pragma unroll
            for (int j = 0; j < 8; ++j) {
                int p = t * 32 + g * 8 + j;
                float w = (c < NH) ? Wb[p * NH + c] : 0.f;
                bfrag[t][j] = (short)f2bf(w);
            }
        }
        const float* src = pair + (cellbase + c) * (long)DP + g * 8;
        float4 x0[4], x1[4];
#pragma unroll
        for (int t = 0; t < 4; ++t) {
            x0[t] = *reinterpret_cast<const float4*>(src + 32 * t);
            x1[t] = *reinterpret_cast<const float4*>(src + 32 * t + 4);
        }
        v4f acc = {0.f, 0.f, 0.f, 0.f};
#pragma unroll
        for (int t = 0; t < 4; ++t) {
            v8s a;
            a[0] = (short)f2bf(x0[t].x); a[1] = (short)f2bf(x0[t].y);
            a[2] = (short)f2bf(x0[t].z); a[3] = (short)f2bf(x0[t].w);
            a[4] = (short)f2bf(x1[t].x); a[5] = (short)f2bf(x1[t].y);
            a[6] = (short)f2bf(x1[t].z); a[7] = (short)f2bf(x1[t].w);
            acc = __builtin_amdgcn_mfma_f32_16x16x32_bf16(a, bfrag[t], acc, 0, 0, 0);
        }
        if (c < NH) {
            ushort4 o;
            o.x = f2bf(acc[0]); o.y = f2bf(acc[1]);
            o.z = f2bf(acc[2]); o.w = f2bf(acc[3]);
            *reinterpret_cast<ushort4*>(lg + (long)c * 1048576 + cellbase + g * 4) = o;
        }
    } else if (bid < 18112) {
        // ---------------- weight transpose+cvt: W[K][N] f32 -> WT[N][K] bf16 ----------------
        int id = bid - 16384;
        const float* W; ushort* WT; int Kd, Nd, t;
        if (id < 144)       { W = Wq; WT = qkvT;             Kd = 384;  Nd = 384;  t = id; }
        else if (id < 288)  { W = Wk; WT = qkvT + 384 * 384; Kd = 384;  Nd = 384;  t = id - 144; }
        else if (id < 432)  { W = Wv; WT = qkvT + 768 * 384; Kd = 384;  Nd = 384;  t = id - 288; }
        else if (id < 576)  { W = Wo; WT = WoT;              Kd = 384;  Nd = 384;  t = id - 432; }
        else if (id < 1152) { W = W1; WT = W1T;              Kd = 384;  Nd = 1536; t = id - 576; }
        else                { W = W2; WT = W2T;              Kd = 1536; Nd = 384;  t = id - 1152; }
        const int ktiles = Kd >> 5;
        const int k0 = (t % ktiles) * 32, n0 = (t / ktiles) * 32;
        const int r = tid >> 3, c4 = (tid & 7) * 4;
        float4 v = *reinterpret_cast<const float4*>(W + (long)(k0 + r) * Nd + n0 + c4);
        tile[r][c4 + 0] = v.x; tile[r][c4 + 1] = v.y;
        tile[r][c4 + 2] = v.z; tile[r][c4 + 3] = v.w;
        __syncthreads();
        ushort4 o;
        o.x = f2bf(tile[c4 + 0][r]); o.y = f2bf(tile[c4 + 1][r]);
        o.z = f2bf(tile[c4 + 2][r]); o.w = f2bf(tile[c4 + 3][r]);
        *reinterpret_cast<ushort4*>(WT + (long)(n0 + r) * Kd + k0 + c4) = o;
    } else {
        // ---------------- LN1: 4 rows per block, 1 wave per row ----------------
        const int wid = tid >> 6, lane = tid & 63;
        const int row = (bid - 18112) * 4 + wid;
        const float* xr = s + (long)row * DS;
        float v[6];
        float sm = 0.f;
#pragma unroll
        for (int t = 0; t < 6; ++t) { v[t] = xr[lane + t * 64]; sm += v[t]; }
#pragma unroll
        for (int o = 32; o >= 1; o >>= 1) sm += __shfl_xor(sm, o);
        const float mean = sm * (1.f / DS);
        float q = 0.f;
#pragma unroll
        for (int t = 0; t < 6; ++t) { float d = v[t] - mean; q += d * d; }
#pragma unroll
        for (int o = 32; o >= 1; o >>= 1) q += __shfl_xor(q, o);
        const float rs = rsqrtf(q * (1.f / DS) + 1e-5f);
#pragma unroll
        for (int t = 0; t < 6; ++t) {
            int cc = lane + t * 64;
            sn[(long)row * DS + cc] = f2bf((v[t] - mean) * rs * g_s[cc] + b_s[cc]);
        }
    }
}

// ==================== LayerNorm (standalone, for LN2) ====================
__global__ __launch_bounds__(256) void ln_k(const float* __restrict__ x,
                                            const float* __restrict__ g,
                                            const float* __restrict__ b,
                                            ushort* __restrict__ ybf) {
    const int wid = threadIdx.x >> 6, lane = threadIdx.x & 63;
    const int row = blockIdx.x * 4 + wid;
    const float* xr = x + (long)row * DS;
    float v[6];
    float s = 0.f;
#pragma unroll
    for (int t = 0; t < 6; ++t) { v[t] = xr[lane + t * 64]; s += v[t]; }
#pragma unroll
    for (int o = 32; o >= 1; o >>= 1) s += __shfl_xor(s, o);
    const float mean = s * (1.f / DS);
    float q = 0.f;
#pragma unroll
    for (int t = 0; t < 6; ++t) { float d = v[t] - mean; q += d * d; }
#pragma unroll
    for (int o = 32; o >= 1; o >>= 1) q += __shfl_xor(q, o);
    const float rs = rsqrtf(q * (1.f / DS) + 1e-5f);
#pragma unroll
    for (int t = 0; t < 6; ++t) {
        int c = lane + t * 64;
        ybf[(long)row * DS + c] = f2bf((v[t] - mean) * rs * g[c] + b[c]);
    }
}

// ==================== register-resident bf16 MFMA GEMM ====================
// C[M][N] = A[M][K] @ BT[N][K]^T ; block 256 = 4 waves 2x2 ; wave tile 32x32.
// EPI: 1 f32 store (+bias +res) ; 3 bf16 gelu store (+bias) ; 4 bf16 store
template <int EPI>
__global__ __launch_bounds__(256) void mgemm_k(const ushort* __restrict__ A,
                                               const ushort* __restrict__ BT,
                                               float* __restrict__ Cf,
                                               ushort* __restrict__ Cb,
                                               const float* __restrict__ bias,
                                               const float* __restrict__ res,
                                               int K, int ldc) {
    const int w = threadIdx.x >> 6;
    const int lane = threadIdx.x & 63;
    const int c = lane & 15, g = lane >> 4;
    const int m0 = blockIdx.x * 64 + (w >> 1) * 32;
    const int n0 = blockIdx.y * 64 + (w & 1) * 32;

    v4f acc[2][2];
#pragma unroll
    for (int i = 0; i < 2; ++i)
#pragma unroll
        for (int j = 0; j < 2; ++j) acc[i][j] = (v4f){0.f, 0.f, 0.f, 0.f};

    const ushort* Ap0 = A + (long)(m0 + c) * K + g * 8;
    const ushort* Ap1 = A + (long)(m0 + 16 + c) * K + g * 8;
    const ushort* Bp0 = BT + (long)(n0 + c) * K + g * 8;
    const ushort* Bp1 = BT + (long)(n0 + 16 + c) * K + g * 8;

#pragma unroll 4
    for (int k0 = 0; k0 < K; k0 += 32) {
        v8s a0 = *reinterpret_cast<const v8s*>(Ap0 + k0);
        v8s a1 = *reinterpret_cast<const v8s*>(Ap1 + k0);
        v8s b0 = *reinterpret_cast<const v8s*>(Bp0 + k0);
        v8s b1 = *reinterpret_cast<const v8s*>(Bp1 + k0);
        acc[0][0] = __builtin_amdgcn_mfma_f32_16x16x32_bf16(a0, b0, acc[0][0], 0, 0, 0);
        acc[0][1] = __builtin_amdgcn_mfma_f32_16x16x32_bf16(a0, b1, acc[0][1], 0, 0, 0);
        acc[1][0] = __builtin_amdgcn_mfma_f32_16x16x32_bf16(a1, b0, acc[1][0], 0, 0, 0);
        acc[1][1] = __builtin_amdgcn_mfma_f32_16x16x32_bf16(a1, b1, acc[1][1], 0, 0, 0);
    }

#pragma unroll
    for (int mi = 0; mi < 2; ++mi) {
#pragma unroll
        for (int ni = 0; ni < 2; ++ni) {
#pragma unroll
            for (int r = 0; r < 4; ++r) {
                const int row = m0 + mi * 16 + g * 4 + r;
                const int col = n0 + ni * 16 + c;
                float v = acc[mi][ni][r];
                if (bias) v += bias[col];
                const long idx = (long)row * ldc + col;
                if (EPI == 1) Cf[idx] = v + res[idx];
                else if (EPI == 3) Cb[idx] = f2bf(gelu_exact(v));
                else Cb[idx] = f2bf(v);
            }
        }
    }
}

// ==================== fused flash attention over precomputed bf16 pair-bias ====================
// block = (head, 64 q-rows), 4 waves x 16 rows; V double-buffered, 1 sync/tile.
__global__ __launch_bounds__(256) void flash_k(const ushort* __restrict__ qkv,
                                               const ushort* __restrict__ lg,
                                               ushort* __restrict__ att) {
    const int h = blockIdx.y;
    const int q0 = blockIdx.x * 64;
    const int tid = threadIdx.x;
    const int w = tid >> 6;
    const int lane = tid & 63;
    const int c = lane & 15, g = lane >> 4;
    const float scale = 0.17677669529663688f;

    __shared__ ushort VT[2][32][80];   // V^T per k-tile: [d][k], padded
    __shared__ ushort P[4][16][80];    // per-wave P tile [row][k], padded

    // V-stage indices: 256 threads cover 64 rows x 4 slots of v8s
    const int vrow = tid >> 2;          // 0..63
    const int vslot = tid & 3;          // 0..3
    const ushort* vbase = qkv + (long)vrow * 1152 + 768 + h * 32 + vslot * 8;

    // hoisted Q fragment for this wave's 16 rows
    const v8s aq = *reinterpret_cast<const v8s*>(
        qkv + (long)(q0 + w * 16 + c) * 1152 + h * 32 + g * 8);

    const ushort* lgbase = lg + (long)h * 1048576 + (long)(q0 + w * 16 + g * 4) * 1024;

    v4f acc0 = {0.f, 0.f, 0.f, 0.f};
    v4f acc1 = {0.f, 0.f, 0.f, 0.f};
    float m_run[4], l_run[4];
#pragma unroll
    for (int r = 0; r < 4; ++r) { m_run[r] = -INFINITY; l_run[r] = 0.f; }

    // prologue: stage V tile 0
    {
        v8s vv = *reinterpret_cast<const v8s*>(vbase);
#pragma unroll
        for (int j = 0; j < 8; ++j) VT[0][vslot * 8 + j][vrow] = (ushort)vv[j];
    }
    __syncthreads();

    for (int kt = 0; kt < 16; ++kt) {
        const int k0 = kt * 64;
        const int cur = kt & 1;

        // issue next V-tile load early (latency hides under QK/softmax)
        v8s vnext;
        const bool have_next = (kt < 15);
        if (have_next)
            vnext = *reinterpret_cast<const v8s*>(vbase + (long)(k0 + 64) * 1152);

        // issue bias loads early (bf16)
        ushort bl[16];
        const ushort* lgb = lgbase + k0;
#pragma unroll
        for (int nf = 0; nf < 4; ++nf)
#pragma unroll
            for (int r = 0; r < 4; ++r)
                bl[nf * 4 + r] = lgb[(long)r * 1024 + nf * 16 + c];

        // ---- QK^T: 4 MFMA over 16-key subtiles ----
        v4f sfr[4];
#pragma unroll
        for (int nf = 0; nf < 4; ++nf) {
            v8s bk = *reinterpret_cast<const v8s*>(
                qkv + (long)(k0 + nf * 16 + c) * 1152 + 384 + h * 32 + g * 8);
            v4f z = {0.f, 0.f, 0.f, 0.f};
            sfr[nf] = __builtin_amdgcn_mfma_f32_16x16x32_bf16(aq, bk, z, 0, 0, 0);
        }

        // ---- bias + scale, row max ----
        float p[4][4];
        float mx[4];
#pragma unroll
        for (int r = 0; r < 4; ++r) mx[r] = -INFINITY;
#pragma unroll
        for (int nf = 0; nf < 4; ++nf) {
#pragma unroll
            for (int r = 0; r < 4; ++r) {
                float sv = sfr[nf][r] * scale + bf2f(bl[nf * 4 + r]);
                p[nf][r] = sv;
                mx[r] = fmaxf(mx[r], sv);
            }
        }
#pragma unroll
        for (int r = 0; r < 4; ++r) {
            mx[r] = fmaxf(mx[r], __shfl_xor(mx[r], 1));
            mx[r] = fmaxf(mx[r], __shfl_xor(mx[r], 2));
            mx[r] = fmaxf(mx[r], __shfl_xor(mx[r], 4));
            mx[r] = fmaxf(mx[r], __shfl_xor(mx[r], 8));
        }

        // ---- online update ----
        float ts[4];
#pragma unroll
        for (int r = 0; r < 4; ++r) {
            const float mnew = fmaxf(m_run[r], mx[r]);
            const float ef = __expf(m_run[r] - mnew);
            m_run[r] = mnew;
            float t = 0.f;
#pragma unroll
            for (int nf = 0; nf < 4; ++nf) {
                p[nf][r] = __expf(p[nf][r] - mnew);
                t += p[nf][r];
            }
            ts[r] = t;
            acc0[r] *= ef; acc1[r] *= ef;
            l_run[r] *= ef;
        }
#pragma unroll
        for (int r = 0; r < 4; ++r) {
            ts[r] += __shfl_xor(ts[r], 1);
            ts[r] += __shfl_xor(ts[r], 2);
            ts[r] += __shfl_xor(ts[r], 4);
            ts[r] += __shfl_xor(ts[r], 8);
            l_run[r] += ts[r];
        }

        // ---- stage next V tile into the other buffer ----
        if (have_next) {
#pragma unroll
            for (int j = 0; j < 8; ++j) VT[cur ^ 1][vslot * 8 + j][vrow] = (ushort)vnext[j];
        }

        // ---- P -> LDS (bf16) ----
#pragma unroll
        for (int nf = 0; nf < 4; ++nf)
#pragma unroll
            for (int r = 0; r < 4; ++r)
                P[w][g * 4 + r][nf * 16 + c] = f2bf(p[nf][r]);

        // ---- PV from current V buffer ----
        v8s pa0 = *reinterpret_cast<const v8s*>(&P[w][c][g * 8]);
        v8s pa1 = *reinterpret_cast<const v8s*>(&P[w][c][32 + g * 8]);
        v8s v00 = *reinterpret_cast<const v8s*>(&VT[cur][c][g * 8]);
        v8s v01 = *reinterpret_cast<const v8s*>(&VT[cur][c][32 + g * 8]);
        v8s v10 = *reinterpret_cast<const v8s*>(&VT[cur][c + 16][g * 8]);
        v8s v11 = *reinterpret_cast<const v8s*>(&VT[cur][c + 16][32 + g * 8]);
        acc0 = __builtin_amdgcn_mfma_f32_16x16x32_bf16(pa0, v00, acc0, 0, 0, 0);
        acc0 = __builtin_amdgcn_mfma_f32_16x16x32_bf16(pa1, v01, acc0, 0, 0, 0);
        acc1 = __builtin_amdgcn_mfma_f32_16x16x32_bf16(pa0, v10, acc1, 0, 0, 0);
        acc1 = __builtin_amdgcn_mfma_f32_16x16x32_bf16(pa1, v11, acc1, 0, 0, 0);

        __syncthreads();
    }

#pragma unroll
    for (int r = 0; r < 4; ++r) {
        const float inv = 1.f / l_run[r];
        const long row = q0 + w * 16 + g * 4 + r;
        att[row * DS + h * 32 + c] = f2bf(acc0[r] * inv);
        att[row * DS + h * 32 + 16 + c] = f2bf(acc1[r] * inv);
    }
}

extern "C" void kernel_launch(void* const* d_in, const int* in_sizes, int n_in,
                              void* d_out, int out_size, void* d_ws, size_t ws_size,
                              hipStream_t stream) {
    const float* s    = (const float*)d_in[0];
    const float* pair = (const float*)d_in[1];
    const float* g_s = (const float*)d_in[3];
    const float* b_s = (const float*)d_in[4];
    const float* Wq  = (const float*)d_in[5];
    const float* Wk  = (const float*)d_in[6];
    const float* Wv  = (const float*)d_in[7];
    const float* Wb  = (const float*)d_in[8];
    const float* Wo  = (const float*)d_in[9];
    const float* bo  = (const float*)d_in[10];
    const float* g_f = (const float*)d_in[11];
    const float* b_f = (const float*)d_in[12];
    const float* W1  = (const float*)d_in[13];
    const float* b1  = (const float*)d_in[14];
    const float* W2  = (const float*)d_in[15];
    const float* b2  = (const float*)d_in[16];
    float* out = (float*)d_out;

    char* ws = (char*)d_ws;
    ushort* lg   = (ushort*)ws;                         ws += 25165824;  // 12*1024*1024*2
    float*  s1   = (float*)ws;                          ws += 1572864;   // 1024*384*4
    ushort* qkv  = (ushort*)ws;                         ws += 2359296;   // 1024*1152*2
    ushort* sn   = (ushort*)ws;                         ws += 786432;
    ushort* hn   = (ushort*)ws;                         ws += 786432;
    ushort* attb = (ushort*)ws;                         ws += 786432;
    ushort* t1   = (ushort*)ws;                         ws += 3145728;   // 1024*1536*2
    ushort* qkvT = (ushort*)ws;                         ws += 884736;    // 1152*384*2
    ushort* WoT  = (ushort*)ws;                         ws += 294912;
    ushort* W1T  = (ushort*)ws;                         ws += 1179648;   // 1536*384*2
    ushort* W2T  = (ushort*)ws;                         ws += 1179648;   // 384*1536*2

    const dim3 blk(256);

    // 1) fused prep: pairb + all weight cvts + LN1
    prep_k<<<dim3(18368), blk, 0, stream>>>(pair, Wb, lg, s, g_s, b_s, sn,
                                            Wq, Wk, Wv, Wo, W1, W2,
                                            qkvT, WoT, W1T, W2T);

    // 2) QKV: qkv[1024][1152] bf16
    mgemm_k<4><<<dim3(16, 18), blk, 0, stream>>>(sn, qkvT, nullptr, qkv,
                                                 nullptr, nullptr, 384, 1152);

    // 3) fused attention
    flash_k<<<dim3(16, 12), blk, 0, stream>>>(qkv, lg, attb);

    // 4) s1 = att @ Wo + bo + s
    mgemm_k<1><<<dim3(16, 6), blk, 0, stream>>>(attb, WoT, s1, nullptr,
                                                bo, s, 384, 384);

    // 5) LN2 -> hn (bf16)
    ln_k<<<dim3(256), blk, 0, stream>>>(s1, g_f, b_f, hn);

    // 6) t1 = gelu(hn @ W1 + b1) (bf16)
    mgemm_k<3><<<dim3(16, 24), blk, 0, stream>>>(hn, W1T, nullptr, t1,
                                                 b1, nullptr, 384, 1536);

    // 7) out = t1 @ W2 + b2 + s1
    mgemm_k<1><<<dim3(16, 6), blk, 0, stream>>>(t1, W2T, out, nullptr,
                                                b2, s1, 1536, 384);
}

// Round 4
// 252.128 us; speedup vs baseline: 2.0599x; 1.0740x over previous
//
#include <hip/hip_runtime.h>
#include <hip/hip_bf16.h>
#include <math.h>

typedef short v8s __attribute__((ext_vector_type(8)));
typedef float v4f __attribute__((ext_vector_type(4)));

#define LSEQ 1024
#define DS 384
#define NH 12
#define HD 32
#define DP 128

static __device__ inline ushort f2bf(float f) {
    __hip_bfloat16 h = __float2bfloat16(f);
    return *reinterpret_cast<ushort*>(&h);
}
static __device__ inline float bf2f(ushort u) {
    return __uint_as_float(((unsigned int)u) << 16);
}
static __device__ inline float gelu_exact(float x) {
    return 0.5f * x * (1.0f + erff(x * 0.70710678118654752f));
}

// ==================== fused prep ====================
// [0,16384) pairb ; [16384,18112) weight cvt ; [18112,18368) LN1 ; [18368,18752) s1 = s + bo
__global__ __launch_bounds__(256) void prep_k(const float* __restrict__ pair,
                                              const float* __restrict__ Wb,
                                              ushort* __restrict__ lg,
                                              const float* __restrict__ s,
                                              const float* __restrict__ g_s,
                                              const float* __restrict__ b_s,
                                              ushort* __restrict__ sn,
                                              const float* __restrict__ Wq,
                                              const float* __restrict__ Wk,
                                              const float* __restrict__ Wv,
                                              const float* __restrict__ Wo,
                                              const float* __restrict__ W1,
                                              const float* __restrict__ W2,
                                              ushort* __restrict__ qkvT,
                                              ushort* __restrict__ WoT,
                                              ushort* __restrict__ W1T,
                                              ushort* __restrict__ W2T,
                                              const float* __restrict__ bo,
                                              float* __restrict__ s1) {
    __shared__ float tile[32][33];
    const int bid = blockIdx.x;
    const int tid = threadIdx.x;

    if (bid < 16384) {
        // ---------------- pair bias via MFMA 16x16x32 bf16 ----------------
        const int lane = tid & 63;
        const int wid = tid >> 6;
        const int c = lane & 15;
        const int g = lane >> 4;
        const long cellbase = ((long)bid * 4 + wid) * 16;

        v8s bfrag[4];
#pragma unroll
        for (int t = 0; t < 4; ++t) {
#pragma unroll
            for (int j = 0; j < 8; ++j) {
                int p = t * 32 + g * 8 + j;
                float w = (c < NH) ? Wb[p * NH + c] : 0.f;
                bfrag[t][j] = (short)f2bf(w);
            }
        }
        const float* src = pair + (cellbase + c) * (long)DP + g * 8;
        float4 x0[4], x1[4];
#pragma unroll
        for (int t = 0; t < 4; ++t) {
            x0[t] = *reinterpret_cast<const float4*>(src + 32 * t);
            x1[t] = *reinterpret_cast<const float4*>(src + 32 * t + 4);
        }
        v4f acc = {0.f, 0.f, 0.f, 0.f};
#pragma unroll
        for (int t = 0; t < 4; ++t) {
            v8s a;
            a[0] = (short)f2bf(x0[t].x); a[1] = (short)f2bf(x0[t].y);
            a[2] = (short)f2bf(x0[t].z); a[3] = (short)f2bf(x0[t].w);
            a[4] = (short)f2bf(x1[t].x); a[5] = (short)f2bf(x1[t].y);
            a[6] = (short)f2bf(x1[t].z); a[7] = (short)f2bf(x1[t].w);
            acc = __builtin_amdgcn_mfma_f32_16x16x32_bf16(a, bfrag[t], acc, 0, 0, 0);
        }
        if (c < NH) {
            ushort4 o;
            o.x = f2bf(acc[0]); o.y = f2bf(acc[1]);
            o.z = f2bf(acc[2]); o.w = f2bf(acc[3]);
            *reinterpret_cast<ushort4*>(lg + (long)c * 1048576 + cellbase + g * 4) = o;
        }
    } else if (bid < 18112) {
        // ---------------- weight transpose+cvt: W[K][N] f32 -> WT[N][K] bf16 ----------------
        int id = bid - 16384;
        const float* W; ushort* WT; int Kd, Nd, t;
        if (id < 144)       { W = Wq; WT = qkvT;             Kd = 384;  Nd = 384;  t = id; }
        else if (id < 288)  { W = Wk; WT = qkvT + 384 * 384; Kd = 384;  Nd = 384;  t = id - 144; }
        else if (id < 432)  { W = Wv; WT = qkvT + 768 * 384; Kd = 384;  Nd = 384;  t = id - 288; }
        else if (id < 576)  { W = Wo; WT = WoT;              Kd = 384;  Nd = 384;  t = id - 432; }
        else if (id < 1152) { W = W1; WT = W1T;              Kd = 384;  Nd = 1536; t = id - 576; }
        else                { W = W2; WT = W2T;              Kd = 1536; Nd = 384;  t = id - 1152; }
        const int ktiles = Kd >> 5;
        const int k0 = (t % ktiles) * 32, n0 = (t / ktiles) * 32;
        const int r = tid >> 3, c4 = (tid & 7) * 4;
        float4 v = *reinterpret_cast<const float4*>(W + (long)(k0 + r) * Nd + n0 + c4);
        tile[r][c4 + 0] = v.x; tile[r][c4 + 1] = v.y;
        tile[r][c4 + 2] = v.z; tile[r][c4 + 3] = v.w;
        __syncthreads();
        ushort4 o;
        o.x = f2bf(tile[c4 + 0][r]); o.y = f2bf(tile[c4 + 1][r]);
        o.z = f2bf(tile[c4 + 2][r]); o.w = f2bf(tile[c4 + 3][r]);
        *reinterpret_cast<ushort4*>(WT + (long)(n0 + r) * Kd + k0 + c4) = o;
    } else if (bid < 18368) {
        // ---------------- LN1 ----------------
        const int wid = tid >> 6, lane = tid & 63;
        const int row = (bid - 18112) * 4 + wid;
        const float* xr = s + (long)row * DS;
        float v[6];
        float sm = 0.f;
#pragma unroll
        for (int t = 0; t < 6; ++t) { v[t] = xr[lane + t * 64]; sm += v[t]; }
#pragma unroll
        for (int o = 32; o >= 1; o >>= 1) sm += __shfl_xor(sm, o);
        const float mean = sm * (1.f / DS);
        float q = 0.f;
#pragma unroll
        for (int t = 0; t < 6; ++t) { float d = v[t] - mean; q += d * d; }
#pragma unroll
        for (int o = 32; o >= 1; o >>= 1) q += __shfl_xor(q, o);
        const float rs = rsqrtf(q * (1.f / DS) + 1e-5f);
#pragma unroll
        for (int t = 0; t < 6; ++t) {
            int cc = lane + t * 64;
            sn[(long)row * DS + cc] = f2bf((v[t] - mean) * rs * g_s[cc] + b_s[cc]);
        }
    } else {
        // ---------------- s1 = s + bo ----------------
        const int i4 = ((bid - 18368) * 256 + tid) * 4;
        float4 sv = *reinterpret_cast<const float4*>(s + i4);
        const int col = i4 % DS;
        float4 bv = *reinterpret_cast<const float4*>(bo + col);
        float4 o;
        o.x = sv.x + bv.x; o.y = sv.y + bv.y;
        o.z = sv.z + bv.z; o.w = sv.w + bv.w;
        *reinterpret_cast<float4*>(s1 + i4) = o;
    }
}

// ==================== LayerNorm (LN2): writes hn bf16 + out_init = x + b2 ====================
__global__ __launch_bounds__(256) void ln_k(const float* __restrict__ x,
                                            const float* __restrict__ g,
                                            const float* __restrict__ b,
                                            ushort* __restrict__ ybf,
                                            float* __restrict__ pre,
                                            const float* __restrict__ pre_bias) {
    const int wid = threadIdx.x >> 6, lane = threadIdx.x & 63;
    const int row = blockIdx.x * 4 + wid;
    const float* xr = x + (long)row * DS;
    float v[6];
    float s = 0.f;
#pragma unroll
    for (int t = 0; t < 6; ++t) { v[t] = xr[lane + t * 64]; s += v[t]; }
#pragma unroll
    for (int o = 32; o >= 1; o >>= 1) s += __shfl_xor(s, o);
    const float mean = s * (1.f / DS);
    float q = 0.f;
#pragma unroll
    for (int t = 0; t < 6; ++t) { float d = v[t] - mean; q += d * d; }
#pragma unroll
    for (int o = 32; o >= 1; o >>= 1) q += __shfl_xor(q, o);
    const float rs = rsqrtf(q * (1.f / DS) + 1e-5f);
#pragma unroll
    for (int t = 0; t < 6; ++t) {
        int c = lane + t * 64;
        ybf[(long)row * DS + c] = f2bf((v[t] - mean) * rs * g[c] + b[c]);
        pre[(long)row * DS + c] = v[t] + pre_bias[c];
    }
}

// ==================== register-resident bf16 MFMA GEMM ====================
// C[M][N] = A[M][K] @ BT[N][K]^T ; 4 waves 2x2 ; wave tile 32x32 ; optional split-K.
// EPI: 1 f32 store (+bias+res) ; 3 bf16 gelu (+bias) ; 4 bf16 store ; 5 f32 atomicAdd
template <int EPI>
__global__ __launch_bounds__(256) void mgemm_k(const ushort* __restrict__ A,
                                               const ushort* __restrict__ BT,
                                               float* __restrict__ Cf,
                                               ushort* __restrict__ Cb,
                                               const float* __restrict__ bias,
                                               const float* __restrict__ res,
                                               int K, int ldc, int ksplit) {
    const int w = threadIdx.x >> 6;
    const int lane = threadIdx.x & 63;
    const int c = lane & 15, g = lane >> 4;
    const int m0 = blockIdx.x * 64 + (w >> 1) * 32;
    const int n0 = blockIdx.y * 64 + (w & 1) * 32;
    const int kc = K / ksplit;
    const int kbeg = blockIdx.z * kc, kend = kbeg + kc;

    v4f acc[2][2];
#pragma unroll
    for (int i = 0; i < 2; ++i)
#pragma unroll
        for (int j = 0; j < 2; ++j) acc[i][j] = (v4f){0.f, 0.f, 0.f, 0.f};

    const ushort* Ap0 = A + (long)(m0 + c) * K + g * 8;
    const ushort* Ap1 = A + (long)(m0 + 16 + c) * K + g * 8;
    const ushort* Bp0 = BT + (long)(n0 + c) * K + g * 8;
    const ushort* Bp1 = BT + (long)(n0 + 16 + c) * K + g * 8;

#pragma unroll 4
    for (int k0 = kbeg; k0 < kend; k0 += 32) {
        v8s a0 = *reinterpret_cast<const v8s*>(Ap0 + k0);
        v8s a1 = *reinterpret_cast<const v8s*>(Ap1 + k0);
        v8s b0 = *reinterpret_cast<const v8s*>(Bp0 + k0);
        v8s b1 = *reinterpret_cast<const v8s*>(Bp1 + k0);
        acc[0][0] = __builtin_amdgcn_mfma_f32_16x16x32_bf16(a0, b0, acc[0][0], 0, 0, 0);
        acc[0][1] = __builtin_amdgcn_mfma_f32_16x16x32_bf16(a0, b1, acc[0][1], 0, 0, 0);
        acc[1][0] = __builtin_amdgcn_mfma_f32_16x16x32_bf16(a1, b0, acc[1][0], 0, 0, 0);
        acc[1][1] = __builtin_amdgcn_mfma_f32_16x16x32_bf16(a1, b1, acc[1][1], 0, 0, 0);
    }

#pragma unroll
    for (int mi = 0; mi < 2; ++mi) {
#pragma unroll
        for (int ni = 0; ni < 2; ++ni) {
#pragma unroll
            for (int r = 0; r < 4; ++r) {
                const int row = m0 + mi * 16 + g * 4 + r;
                const int col = n0 + ni * 16 + c;
                float v = acc[mi][ni][r];
                if (bias) v += bias[col];
                const long idx = (long)row * ldc + col;
                if (EPI == 1) Cf[idx] = v + res[idx];
                else if (EPI == 3) Cb[idx] = f2bf(gelu_exact(v));
                else if (EPI == 4) Cb[idx] = f2bf(v);
                else atomicAdd(&Cf[idx], v);
            }
        }
    }
}

// ==================== fused flash attention, LDS-staged double-buffered bias + V ====================
__global__ __launch_bounds__(256) void flash_k(const ushort* __restrict__ qkv,
                                               const ushort* __restrict__ lg,
                                               ushort* __restrict__ att) {
    const int h = blockIdx.y;
    const int q0 = blockIdx.x * 64;
    const int tid = threadIdx.x;
    const int w = tid >> 6;
    const int lane = tid & 63;
    const int c = lane & 15, g = lane >> 4;
    const float scale = 0.17677669529663688f;

    __shared__ ushort VT[2][32][80];   // V^T per k-tile: [d][k]
    __shared__ ushort BL[2][64][72];   // bias tile [q][k], stride 72 (16B-aligned, low conflict)
    __shared__ ushort P[4][16][80];    // per-wave P tile [row][k]

    // cooperative staging split: row tid>>2 (0..63), slot tid&3 (16 ushorts each)
    const int vrow = tid >> 2;
    const int vslot = tid & 3;
    const ushort* vbase = qkv + (long)vrow * 1152 + 768 + h * 32 + vslot * 8;
    const ushort* bbase = lg + (long)h * 1048576 + (long)(q0 + vrow) * 1024 + vslot * 16;

    // hoisted Q fragment for this wave's 16 rows
    const v8s aq = *reinterpret_cast<const v8s*>(
        qkv + (long)(q0 + w * 16 + c) * 1152 + h * 32 + g * 8);

    v4f acc0 = {0.f, 0.f, 0.f, 0.f};
    v4f acc1 = {0.f, 0.f, 0.f, 0.f};
    float m_run[4], l_run[4];
#pragma unroll
    for (int r = 0; r < 4; ++r) { m_run[r] = -INFINITY; l_run[r] = 0.f; }

    // prologue: stage V + bias for tile 0
    {
        v8s vv = *reinterpret_cast<const v8s*>(vbase);
#pragma unroll
        for (int j = 0; j < 8; ++j) VT[0][vslot * 8 + j][vrow] = (ushort)vv[j];
        v8s b0 = *reinterpret_cast<const v8s*>(bbase);
        v8s b1 = *reinterpret_cast<const v8s*>(bbase + 8);
        *reinterpret_cast<v8s*>(&BL[0][vrow][vslot * 16]) = b0;
        *reinterpret_cast<v8s*>(&BL[0][vrow][vslot * 16 + 8]) = b1;
    }
    __syncthreads();

    for (int kt = 0; kt < 16; ++kt) {
        const int k0 = kt * 64;
        const int cur = kt & 1, nxt = cur ^ 1;
        const bool have_next = (kt < 15);

        // issue next-tile global loads early (hide under QK/softmax)
        v8s vnext, bn0, bn1;
        if (have_next) {
            vnext = *reinterpret_cast<const v8s*>(vbase + (long)(k0 + 64) * 1152);
            bn0 = *reinterpret_cast<const v8s*>(bbase + k0 + 64);
            bn1 = *reinterpret_cast<const v8s*>(bbase + k0 + 64 + 8);
        }

        // ---- QK^T: 4 MFMA over 16-key subtiles ----
        v4f sfr[4];
#pragma unroll
        for (int nf = 0; nf < 4; ++nf) {
            v8s bk = *reinterpret_cast<const v8s*>(
                qkv + (long)(k0 + nf * 16 + c) * 1152 + 384 + h * 32 + g * 8);
            v4f z = {0.f, 0.f, 0.f, 0.f};
            sfr[nf] = __builtin_amdgcn_mfma_f32_16x16x32_bf16(aq, bk, z, 0, 0, 0);
        }

        // ---- bias (from LDS) + scale, row max ----
        float p[4][4];
        float mx[4];
#pragma unroll
        for (int r = 0; r < 4; ++r) mx[r] = -INFINITY;
#pragma unroll
        for (int nf = 0; nf < 4; ++nf) {
#pragma unroll
            for (int r = 0; r < 4; ++r) {
                float sv = sfr[nf][r] * scale + bf2f(BL[cur][w * 16 + g * 4 + r][nf * 16 + c]);
                p[nf][r] = sv;
                mx[r] = fmaxf(mx[r], sv);
            }
        }
#pragma unroll
        for (int r = 0; r < 4; ++r) {
            mx[r] = fmaxf(mx[r], __shfl_xor(mx[r], 1));
            mx[r] = fmaxf(mx[r], __shfl_xor(mx[r], 2));
            mx[r] = fmaxf(mx[r], __shfl_xor(mx[r], 4));
            mx[r] = fmaxf(mx[r], __shfl_xor(mx[r], 8));
        }

        // ---- online update ----
        float ts[4];
#pragma unroll
        for (int r = 0; r < 4; ++r) {
            const float mnew = fmaxf(m_run[r], mx[r]);
            const float ef = __expf(m_run[r] - mnew);
            m_run[r] = mnew;
            float t = 0.f;
#pragma unroll
            for (int nf = 0; nf < 4; ++nf) {
                p[nf][r] = __expf(p[nf][r] - mnew);
                t += p[nf][r];
            }
            ts[r] = t;
            acc0[r] *= ef; acc1[r] *= ef;
            l_run[r] *= ef;
        }
#pragma unroll
        for (int r = 0; r < 4; ++r) {
            ts[r] += __shfl_xor(ts[r], 1);
            ts[r] += __shfl_xor(ts[r], 2);
            ts[r] += __shfl_xor(ts[r], 4);
            ts[r] += __shfl_xor(ts[r], 8);
            l_run[r] += ts[r];
        }

        // ---- stage next tile's V + bias ----
        if (have_next) {
#pragma unroll
            for (int j = 0; j < 8; ++j) VT[nxt][vslot * 8 + j][vrow] = (ushort)vnext[j];
            *reinterpret_cast<v8s*>(&BL[nxt][vrow][vslot * 16]) = bn0;
            *reinterpret_cast<v8s*>(&BL[nxt][vrow][vslot * 16 + 8]) = bn1;
        }

        // ---- P -> LDS (bf16, per-wave) ----
#pragma unroll
        for (int nf = 0; nf < 4; ++nf)
#pragma unroll
            for (int r = 0; r < 4; ++r)
                P[w][g * 4 + r][nf * 16 + c] = f2bf(p[nf][r]);

        // ---- PV from current V buffer ----
        v8s pa0 = *reinterpret_cast<const v8s*>(&P[w][c][g * 8]);
        v8s pa1 = *reinterpret_cast<const v8s*>(&P[w][c][32 + g * 8]);
        v8s v00 = *reinterpret_cast<const v8s*>(&VT[cur][c][g * 8]);
        v8s v01 = *reinterpret_cast<const v8s*>(&VT[cur][c][32 + g * 8]);
        v8s v10 = *reinterpret_cast<const v8s*>(&VT[cur][c + 16][g * 8]);
        v8s v11 = *reinterpret_cast<const v8s*>(&VT[cur][c + 16][32 + g * 8]);
        acc0 = __builtin_amdgcn_mfma_f32_16x16x32_bf16(pa0, v00, acc0, 0, 0, 0);
        acc0 = __builtin_amdgcn_mfma_f32_16x16x32_bf16(pa1, v01, acc0, 0, 0, 0);
        acc1 = __builtin_amdgcn_mfma_f32_16x16x32_bf16(pa0, v10, acc1, 0, 0, 0);
        acc1 = __builtin_amdgcn_mfma_f32_16x16x32_bf16(pa1, v11, acc1, 0, 0, 0);

        __syncthreads();
    }

#pragma unroll
    for (int r = 0; r < 4; ++r) {
        const float inv = 1.f / l_run[r];
        const long row = q0 + w * 16 + g * 4 + r;
        att[row * DS + h * 32 + c] = f2bf(acc0[r] * inv);
        att[row * DS + h * 32 + 16 + c] = f2bf(acc1[r] * inv);
    }
}

extern "C" void kernel_launch(void* const* d_in, const int* in_sizes, int n_in,
                              void* d_out, int out_size, void* d_ws, size_t ws_size,
                              hipStream_t stream) {
    const float* s    = (const float*)d_in[0];
    const float* pair = (const float*)d_in[1];
    const float* g_s = (const float*)d_in[3];
    const float* b_s = (const float*)d_in[4];
    const float* Wq  = (const float*)d_in[5];
    const float* Wk  = (const float*)d_in[6];
    const float* Wv  = (const float*)d_in[7];
    const float* Wb  = (const float*)d_in[8];
    const float* Wo  = (const float*)d_in[9];
    const float* bo  = (const float*)d_in[10];
    const float* g_f = (const float*)d_in[11];
    const float* b_f = (const float*)d_in[12];
    const float* W1  = (const float*)d_in[13];
    const float* b1  = (const float*)d_in[14];
    const float* W2  = (const float*)d_in[15];
    const float* b2  = (const float*)d_in[16];
    float* out = (float*)d_out;

    char* ws = (char*)d_ws;
    ushort* lg   = (ushort*)ws;                         ws += 25165824;  // 12*1024*1024*2
    float*  s1   = (float*)ws;                          ws += 1572864;   // 1024*384*4
    ushort* qkv  = (ushort*)ws;                         ws += 2359296;   // 1024*1152*2
    ushort* sn   = (ushort*)ws;                         ws += 786432;
    ushort* hn   = (ushort*)ws;                         ws += 786432;
    ushort* attb = (ushort*)ws;                         ws += 786432;
    ushort* t1   = (ushort*)ws;                         ws += 3145728;   // 1024*1536*2
    ushort* qkvT = (ushort*)ws;                         ws += 884736;    // 1152*384*2
    ushort* WoT  = (ushort*)ws;                         ws += 294912;
    ushort* W1T  = (ushort*)ws;                         ws += 1179648;   // 1536*384*2
    ushort* W2T  = (ushort*)ws;                         ws += 1179648;   // 384*1536*2

    const dim3 blk(256);

    // 1) fused prep: pairb + weight cvts + LN1 + s1 = s + bo
    prep_k<<<dim3(18752), blk, 0, stream>>>(pair, Wb, lg, s, g_s, b_s, sn,
                                            Wq, Wk, Wv, Wo, W1, W2,
                                            qkvT, WoT, W1T, W2T, bo, s1);

    // 2) QKV (bf16)
    mgemm_k<4><<<dim3(16, 18, 1), blk, 0, stream>>>(sn, qkvT, nullptr, qkv,
                                                    nullptr, nullptr, 384, 1152, 1);

    // 3) fused attention
    flash_k<<<dim3(16, 12), blk, 0, stream>>>(qkv, lg, attb);

    // 4) s1 += att @ Wo   (split-K=2, atomic; s1 pre-initialized to s + bo)
    mgemm_k<5><<<dim3(16, 6, 2), blk, 0, stream>>>(attb, WoT, s1, nullptr,
                                                   nullptr, nullptr, 384, 384, 2);

    // 5) LN2 -> hn (bf16) ; out = s1 + b2
    ln_k<<<dim3(256), blk, 0, stream>>>(s1, g_f, b_f, hn, out, b2);

    // 6) t1 = gelu(hn @ W1 + b1) (bf16)
    mgemm_k<3><<<dim3(16, 24, 1), blk, 0, stream>>>(hn, W1T, nullptr, t1,
                                                    b1, nullptr, 384, 1536, 1);

    // 7) out += t1 @ W2   (split-K=2, atomic; out pre-initialized to s1 + b2)
    mgemm_k<5><<<dim3(16, 6, 2), blk, 0, stream>>>(t1, W2T, out, nullptr,
                                                   nullptr, nullptr, 1536, 384, 2);
}

// Round 5
// 227.615 us; speedup vs baseline: 2.2818x; 1.1077x over previous
//
#include <hip/hip_runtime.h>
#include <hip/hip_bf16.h>
#include <math.h>

typedef short v8s __attribute__((ext_vector_type(8)));
typedef float v4f __attribute__((ext_vector_type(4)));

#define LSEQ 1024
#define DS 384
#define NH 12
#define HD 32
#define DP 128

static __device__ inline ushort f2bf(float f) {
    __hip_bfloat16 h = __float2bfloat16(f);
    return *reinterpret_cast<ushort*>(&h);
}
static __device__ inline float bf2f(ushort u) {
    return __uint_as_float(((unsigned int)u) << 16);
}
static __device__ inline float gelu_exact(float x) {
    return 0.5f * x * (1.0f + erff(x * 0.70710678118654752f));
}

// ==================== prep2: wcvt [0,1728) + LN1 [1728,1984) + s1=s+bo [1984,2368) ====================
__global__ __launch_bounds__(256) void prep2_k(const float* __restrict__ s,
                                               const float* __restrict__ g_s,
                                               const float* __restrict__ b_s,
                                               ushort* __restrict__ sn,
                                               const float* __restrict__ Wq,
                                               const float* __restrict__ Wk,
                                               const float* __restrict__ Wv,
                                               const float* __restrict__ Wo,
                                               const float* __restrict__ W1,
                                               const float* __restrict__ W2,
                                               ushort* __restrict__ qkvT,
                                               ushort* __restrict__ WoT,
                                               ushort* __restrict__ W1T,
                                               ushort* __restrict__ W2T,
                                               const float* __restrict__ bo,
                                               float* __restrict__ s1) {
    __shared__ float tile[32][33];
    const int bid = blockIdx.x;
    const int tid = threadIdx.x;

    if (bid < 1728) {
        int id = bid;
        const float* W; ushort* WT; int Kd, Nd, t;
        if (id < 144)       { W = Wq; WT = qkvT;             Kd = 384;  Nd = 384;  t = id; }
        else if (id < 288)  { W = Wk; WT = qkvT + 384 * 384; Kd = 384;  Nd = 384;  t = id - 144; }
        else if (id < 432)  { W = Wv; WT = qkvT + 768 * 384; Kd = 384;  Nd = 384;  t = id - 288; }
        else if (id < 576)  { W = Wo; WT = WoT;              Kd = 384;  Nd = 384;  t = id - 432; }
        else if (id < 1152) { W = W1; WT = W1T;              Kd = 384;  Nd = 1536; t = id - 576; }
        else                { W = W2; WT = W2T;              Kd = 1536; Nd = 384;  t = id - 1152; }
        const int ktiles = Kd >> 5;
        const int k0 = (t % ktiles) * 32, n0 = (t / ktiles) * 32;
        const int r = tid >> 3, c4 = (tid & 7) * 4;
        float4 v = *reinterpret_cast<const float4*>(W + (long)(k0 + r) * Nd + n0 + c4);
        tile[r][c4 + 0] = v.x; tile[r][c4 + 1] = v.y;
        tile[r][c4 + 2] = v.z; tile[r][c4 + 3] = v.w;
        __syncthreads();
        ushort4 o;
        o.x = f2bf(tile[c4 + 0][r]); o.y = f2bf(tile[c4 + 1][r]);
        o.z = f2bf(tile[c4 + 2][r]); o.w = f2bf(tile[c4 + 3][r]);
        *reinterpret_cast<ushort4*>(WT + (long)(n0 + r) * Kd + k0 + c4) = o;
    } else if (bid < 1984) {
        const int wid = tid >> 6, lane = tid & 63;
        const int row = (bid - 1728) * 4 + wid;
        const float* xr = s + (long)row * DS;
        float v[6];
        float sm = 0.f;
#pragma unroll
        for (int t = 0; t < 6; ++t) { v[t] = xr[lane + t * 64]; sm += v[t]; }
#pragma unroll
        for (int o = 32; o >= 1; o >>= 1) sm += __shfl_xor(sm, o);
        const float mean = sm * (1.f / DS);
        float q = 0.f;
#pragma unroll
        for (int t = 0; t < 6; ++t) { float d = v[t] - mean; q += d * d; }
#pragma unroll
        for (int o = 32; o >= 1; o >>= 1) q += __shfl_xor(q, o);
        const float rs = rsqrtf(q * (1.f / DS) + 1e-5f);
#pragma unroll
        for (int t = 0; t < 6; ++t) {
            int cc = lane + t * 64;
            sn[(long)row * DS + cc] = f2bf((v[t] - mean) * rs * g_s[cc] + b_s[cc]);
        }
    } else {
        const int i4 = ((bid - 1984) * 256 + tid) * 4;
        float4 sv = *reinterpret_cast<const float4*>(s + i4);
        const int col = i4 % DS;
        float4 bv = *reinterpret_cast<const float4*>(bo + col);
        float4 o;
        o.x = sv.x + bv.x; o.y = sv.y + bv.y;
        o.z = sv.z + bv.z; o.w = sv.w + bv.w;
        *reinterpret_cast<float4*>(s1 + i4) = o;
    }
}

// ==================== LayerNorm (LN2): hn bf16 + out_init = x + b2 ====================
__global__ __launch_bounds__(256) void ln_k(const float* __restrict__ x,
                                            const float* __restrict__ g,
                                            const float* __restrict__ b,
                                            ushort* __restrict__ ybf,
                                            float* __restrict__ pre,
                                            const float* __restrict__ pre_bias) {
    const int wid = threadIdx.x >> 6, lane = threadIdx.x & 63;
    const int row = blockIdx.x * 4 + wid;
    const float* xr = x + (long)row * DS;
    float v[6];
    float s = 0.f;
#pragma unroll
    for (int t = 0; t < 6; ++t) { v[t] = xr[lane + t * 64]; s += v[t]; }
#pragma unroll
    for (int o = 32; o >= 1; o >>= 1) s += __shfl_xor(s, o);
    const float mean = s * (1.f / DS);
    float q = 0.f;
#pragma unroll
    for (int t = 0; t < 6; ++t) { float d = v[t] - mean; q += d * d; }
#pragma unroll
    for (int o = 32; o >= 1; o >>= 1) q += __shfl_xor(q, o);
    const float rs = rsqrtf(q * (1.f / DS) + 1e-5f);
#pragma unroll
    for (int t = 0; t < 6; ++t) {
        int c = lane + t * 64;
        ybf[(long)row * DS + c] = f2bf((v[t] - mean) * rs * g[c] + b[c]);
        pre[(long)row * DS + c] = v[t] + pre_bias[c];
    }
}

// ==================== register-resident bf16 MFMA GEMM ====================
// EPI: 1 f32 store (+bias+res) ; 3 bf16 gelu (+bias) ; 4 bf16 store ; 5 f32 atomicAdd
template <int EPI>
__global__ __launch_bounds__(256) void mgemm_k(const ushort* __restrict__ A,
                                               const ushort* __restrict__ BT,
                                               float* __restrict__ Cf,
                                               ushort* __restrict__ Cb,
                                               const float* __restrict__ bias,
                                               const float* __restrict__ res,
                                               int K, int ldc, int ksplit) {
    const int w = threadIdx.x >> 6;
    const int lane = threadIdx.x & 63;
    const int c = lane & 15, g = lane >> 4;
    const int m0 = blockIdx.x * 64 + (w >> 1) * 32;
    const int n0 = blockIdx.y * 64 + (w & 1) * 32;
    const int kc = K / ksplit;
    const int kbeg = blockIdx.z * kc, kend = kbeg + kc;

    v4f acc[2][2];
#pragma unroll
    for (int i = 0; i < 2; ++i)
#pragma unroll
        for (int j = 0; j < 2; ++j) acc[i][j] = (v4f){0.f, 0.f, 0.f, 0.f};

    const ushort* Ap0 = A + (long)(m0 + c) * K + g * 8;
    const ushort* Ap1 = A + (long)(m0 + 16 + c) * K + g * 8;
    const ushort* Bp0 = BT + (long)(n0 + c) * K + g * 8;
    const ushort* Bp1 = BT + (long)(n0 + 16 + c) * K + g * 8;

#pragma unroll 4
    for (int k0 = kbeg; k0 < kend; k0 += 32) {
        v8s a0 = *reinterpret_cast<const v8s*>(Ap0 + k0);
        v8s a1 = *reinterpret_cast<const v8s*>(Ap1 + k0);
        v8s b0 = *reinterpret_cast<const v8s*>(Bp0 + k0);
        v8s b1 = *reinterpret_cast<const v8s*>(Bp1 + k0);
        acc[0][0] = __builtin_amdgcn_mfma_f32_16x16x32_bf16(a0, b0, acc[0][0], 0, 0, 0);
        acc[0][1] = __builtin_amdgcn_mfma_f32_16x16x32_bf16(a0, b1, acc[0][1], 0, 0, 0);
        acc[1][0] = __builtin_amdgcn_mfma_f32_16x16x32_bf16(a1, b0, acc[1][0], 0, 0, 0);
        acc[1][1] = __builtin_amdgcn_mfma_f32_16x16x32_bf16(a1, b1, acc[1][1], 0, 0, 0);
    }

#pragma unroll
    for (int mi = 0; mi < 2; ++mi) {
#pragma unroll
        for (int ni = 0; ni < 2; ++ni) {
#pragma unroll
            for (int r = 0; r < 4; ++r) {
                const int row = m0 + mi * 16 + g * 4 + r;
                const int col = n0 + ni * 16 + c;
                float v = acc[mi][ni][r];
                if (bias) v += bias[col];
                const long idx = (long)row * ldc + col;
                if (EPI == 1) Cf[idx] = v + res[idx];
                else if (EPI == 3) Cb[idx] = f2bf(gelu_exact(v));
                else if (EPI == 4) Cb[idx] = f2bf(v);
                else atomicAdd(&Cf[idx], v);
            }
        }
    }
}

// ==================== fused pair-bias + attention chunk (split softmax) ====================
// grid (32 kc, 32 qb), 128 threads = 2 waves. Wave w: q rows [qb*32 + w*16, +16), keys [kc*32, +32).
// Phase 1: stream pair strip via global_load_lds (swizzled), MFMA bias into wave-local LDS.
// Phase 2: per head: QK^T + bias, local softmax, PV -> partial (m, l, O) to global.
__global__ __launch_bounds__(128) void fa2_k(const float* __restrict__ pair,
                                             const float* __restrict__ Wb,
                                             const ushort* __restrict__ qkv,
                                             float* __restrict__ Opart,
                                             float* __restrict__ ml) {
    __shared__ float stage[2][2048];        // 8 KB per wave
    __shared__ ushort BL[32 * 32 * 12];     // bias [q_local][k_local][head]
    __shared__ ushort P[2][16][34];         // per-wave P tile

    const int kc = blockIdx.x, qb = blockIdx.y;
    const int q0 = qb * 32, k0 = kc * 32;
    const int tid = threadIdx.x;
    const int w = tid >> 6, lane = tid & 63;
    const int c = lane & 15, g = lane >> 4;
    const float scale = 0.17677669529663688f;

    // ---- Wb fragments (proven pairb layout) ----
    v8s bfrag[4];
#pragma unroll
    for (int t2 = 0; t2 < 4; ++t2) {
#pragma unroll
        for (int j = 0; j < 8; ++j) {
            int p = t2 * 32 + g * 8 + j;
            float wv = (c < NH) ? Wb[p * NH + c] : 0.f;
            bfrag[t2][j] = (short)f2bf(wv);
        }
    }

    // ---- Phase 1: 32 tiles (tile = one q row x 16 keys x 128 feats = 8 KB contiguous) ----
    const int xorkey = (c & 7) << 4;
#pragma unroll 1
    for (int t = 0; t < 32; ++t) {
        const int ql = t >> 1, kh = t & 1;
        const long tb = ((long)(q0 + w * 16 + ql) * 1024 + k0 + kh * 16) * 128;
        // drain LDS ops from previous iteration before overwriting stage
        asm volatile("s_waitcnt lgkmcnt(0)" ::: "memory");
#pragma unroll
        for (int j = 0; j < 8; ++j) {
            const int doff = j * 1024 + lane * 16;
            const int loff = doff ^ ((((doff >> 9) & 7)) << 4);
            __builtin_amdgcn_global_load_lds(
                (const __attribute__((address_space(1))) void*)((const char*)(pair + tb) + loff),
                (__attribute__((address_space(3))) void*)(&stage[w][j * 256]),
                16, 0, 0);
        }
        asm volatile("s_waitcnt vmcnt(0)" ::: "memory");

        const char* sw = (const char*)&stage[w][0];
        v4f acc = {0.f, 0.f, 0.f, 0.f};
#pragma unroll
        for (int t2 = 0; t2 < 4; ++t2) {
            const int lo = c * 512 + t2 * 128 + g * 32;
            v4f x0 = *reinterpret_cast<const v4f*>(sw + (lo ^ xorkey));
            v4f x1 = *reinterpret_cast<const v4f*>(sw + ((lo + 16) ^ xorkey));
            v8s a;
            a[0] = (short)f2bf(x0[0]); a[1] = (short)f2bf(x0[1]);
            a[2] = (short)f2bf(x0[2]); a[3] = (short)f2bf(x0[3]);
            a[4] = (short)f2bf(x1[0]); a[5] = (short)f2bf(x1[1]);
            a[6] = (short)f2bf(x1[2]); a[7] = (short)f2bf(x1[3]);
            acc = __builtin_amdgcn_mfma_f32_16x16x32_bf16(a, bfrag[t2], acc, 0, 0, 0);
        }
        // D: row m = key cell (g*4+r), col n = head (c)
        if (c < NH) {
#pragma unroll
            for (int r = 0; r < 4; ++r)
                BL[((w * 16 + ql) * 32 + kh * 16 + g * 4 + r) * 12 + c] = f2bf(acc[r]);
        }
    }
    // wave-local data only -> no barrier needed (compiler handles lgkmcnt on LDS deps)

    // ---- Phase 2: per-head attention chunk ----
    const v8s aq_all[1] = {};  (void)aq_all;
#pragma unroll 1
    for (int h = 0; h < NH; ++h) {
        const v8s aq = *reinterpret_cast<const v8s*>(
            qkv + (long)(q0 + w * 16 + c) * 1152 + h * 32 + g * 8);

        v4f sfr[2];
#pragma unroll
        for (int nf = 0; nf < 2; ++nf) {
            v8s bk = *reinterpret_cast<const v8s*>(
                qkv + (long)(k0 + nf * 16 + c) * 1152 + 384 + h * 32 + g * 8);
            v4f z = {0.f, 0.f, 0.f, 0.f};
            sfr[nf] = __builtin_amdgcn_mfma_f32_16x16x32_bf16(aq, bk, z, 0, 0, 0);
        }

        float p[2][4];
        float mx[4];
#pragma unroll
        for (int r = 0; r < 4; ++r) mx[r] = -INFINITY;
#pragma unroll
        for (int nf = 0; nf < 2; ++nf) {
#pragma unroll
            for (int r = 0; r < 4; ++r) {
                const int qr = w * 16 + g * 4 + r;
                float sv = sfr[nf][r] * scale + bf2f(BL[(qr * 32 + nf * 16 + c) * 12 + h]);
                p[nf][r] = sv;
                mx[r] = fmaxf(mx[r], sv);
            }
        }
#pragma unroll
        for (int r = 0; r < 4; ++r) {
            mx[r] = fmaxf(mx[r], __shfl_xor(mx[r], 1));
            mx[r] = fmaxf(mx[r], __shfl_xor(mx[r], 2));
            mx[r] = fmaxf(mx[r], __shfl_xor(mx[r], 4));
            mx[r] = fmaxf(mx[r], __shfl_xor(mx[r], 8));
        }
        float ls[4];
#pragma unroll
        for (int r = 0; r < 4; ++r) {
            float t0 = 0.f;
#pragma unroll
            for (int nf = 0; nf < 2; ++nf) {
                p[nf][r] = __expf(p[nf][r] - mx[r]);
                t0 += p[nf][r];
            }
            ls[r] = t0;
        }
#pragma unroll
        for (int r = 0; r < 4; ++r) {
            ls[r] += __shfl_xor(ls[r], 1);
            ls[r] += __shfl_xor(ls[r], 2);
            ls[r] += __shfl_xor(ls[r], 4);
            ls[r] += __shfl_xor(ls[r], 8);
        }

        // P -> LDS (rows = q g*4+r, cols = k nf*16+c)
#pragma unroll
        for (int nf = 0; nf < 2; ++nf)
#pragma unroll
            for (int r = 0; r < 4; ++r)
                P[w][g * 4 + r][nf * 16 + c] = f2bf(p[nf][r]);

        const v8s pa = *reinterpret_cast<const v8s*>(&P[w][c][g * 8]);

        // PV: B frag lane c = d col, elems = keys g*8+j (scalar V reads, L2-hot)
        v4f oacc[2];
#pragma unroll
        for (int nf2 = 0; nf2 < 2; ++nf2) {
            v8s vb;
#pragma unroll
            for (int j = 0; j < 8; ++j)
                vb[j] = (short)qkv[(long)(k0 + g * 8 + j) * 1152 + 768 + h * 32 + nf2 * 16 + c];
            v4f z = {0.f, 0.f, 0.f, 0.f};
            oacc[nf2] = __builtin_amdgcn_mfma_f32_16x16x32_bf16(pa, vb, z, 0, 0, 0);
        }

        // store partials
        const long base = ((long)(h * 32 + kc) * 1024 + q0 + w * 16 + g * 4);
#pragma unroll
        for (int r = 0; r < 4; ++r) {
            Opart[(base + r) * 32 + c] = oacc[0][r];
            Opart[(base + r) * 32 + 16 + c] = oacc[1][r];
        }
        if (c == 0) {
#pragma unroll
            for (int r = 0; r < 4; ++r) {
                ml[(base + r) * 2 + 0] = mx[r];
                ml[(base + r) * 2 + 1] = ls[r];
            }
        }
    }
}

// ==================== combine partial softmax chunks ====================
// grid (16 q-chunks, 12 heads), 256 thr: thread -> (q = qc*64 + t>>2, d-octet = (t&3)*8)
__global__ __launch_bounds__(256) void combine_k(const float* __restrict__ Opart,
                                                 const float* __restrict__ ml,
                                                 ushort* __restrict__ att) {
    const int h = blockIdx.y;
    const int q = blockIdx.x * 64 + (threadIdx.x >> 2);
    const int ds = (threadIdx.x & 3) * 8;

    float Mrun = -INFINITY, lsum = 0.f;
    float O[8];
#pragma unroll
    for (int j = 0; j < 8; ++j) O[j] = 0.f;

    for (int kc = 0; kc < 32; ++kc) {
        const long base = ((long)(h * 32 + kc) * 1024 + q);
        const float m = ml[base * 2 + 0];
        const float l = ml[base * 2 + 1];
        const float Mnew = fmaxf(Mrun, m);
        const float fo = __expf(Mrun - Mnew);
        const float fn = __expf(m - Mnew);
        lsum = lsum * fo + l * fn;
        float4 o0 = *reinterpret_cast<const float4*>(Opart + base * 32 + ds);
        float4 o1 = *reinterpret_cast<const float4*>(Opart + base * 32 + ds + 4);
        O[0] = O[0] * fo + fn * o0.x; O[1] = O[1] * fo + fn * o0.y;
        O[2] = O[2] * fo + fn * o0.z; O[3] = O[3] * fo + fn * o0.w;
        O[4] = O[4] * fo + fn * o1.x; O[5] = O[5] * fo + fn * o1.y;
        O[6] = O[6] * fo + fn * o1.z; O[7] = O[7] * fo + fn * o1.w;
        Mrun = Mnew;
    }
    const float inv = 1.f / lsum;
    ushort4 u0, u1;
    u0.x = f2bf(O[0] * inv); u0.y = f2bf(O[1] * inv);
    u0.z = f2bf(O[2] * inv); u0.w = f2bf(O[3] * inv);
    u1.x = f2bf(O[4] * inv); u1.y = f2bf(O[5] * inv);
    u1.z = f2bf(O[6] * inv); u1.w = f2bf(O[7] * inv);
    *reinterpret_cast<ushort4*>(att + (long)q * DS + h * 32 + ds) = u0;
    *reinterpret_cast<ushort4*>(att + (long)q * DS + h * 32 + ds + 4) = u1;
}

extern "C" void kernel_launch(void* const* d_in, const int* in_sizes, int n_in,
                              void* d_out, int out_size, void* d_ws, size_t ws_size,
                              hipStream_t stream) {
    const float* s    = (const float*)d_in[0];
    const float* pair = (const float*)d_in[1];
    const float* g_s = (const float*)d_in[3];
    const float* b_s = (const float*)d_in[4];
    const float* Wq  = (const float*)d_in[5];
    const float* Wk  = (const float*)d_in[6];
    const float* Wv  = (const float*)d_in[7];
    const float* Wb  = (const float*)d_in[8];
    const float* Wo  = (const float*)d_in[9];
    const float* bo  = (const float*)d_in[10];
    const float* g_f = (const float*)d_in[11];
    const float* b_f = (const float*)d_in[12];
    const float* W1  = (const float*)d_in[13];
    const float* b1  = (const float*)d_in[14];
    const float* W2  = (const float*)d_in[15];
    const float* b2  = (const float*)d_in[16];
    float* out = (float*)d_out;

    char* ws = (char*)d_ws;
    float*  Opart = (float*)ws;                        ws += 50331648;  // 12*32*1024*32*4
    float*  mlb   = (float*)ws;                        ws += 3145728;   // 12*32*1024*2*4
    float*  s1    = (float*)ws;                        ws += 1572864;
    ushort* qkv   = (ushort*)ws;                       ws += 2359296;
    ushort* sn    = (ushort*)ws;                       ws += 786432;
    ushort* hn    = (ushort*)ws;                       ws += 786432;
    ushort* attb  = (ushort*)ws;                       ws += 786432;
    ushort* t1    = (ushort*)ws;                       ws += 3145728;
    ushort* qkvT  = (ushort*)ws;                       ws += 884736;
    ushort* WoT   = (ushort*)ws;                       ws += 294912;
    ushort* W1T   = (ushort*)ws;                       ws += 1179648;
    ushort* W2T   = (ushort*)ws;                       ws += 1179648;

    const dim3 blk(256);

    // 1) prep2: weight cvts + LN1 + s1 = s + bo
    prep2_k<<<dim3(2368), blk, 0, stream>>>(s, g_s, b_s, sn,
                                            Wq, Wk, Wv, Wo, W1, W2,
                                            qkvT, WoT, W1T, W2T, bo, s1);

    // 2) QKV (bf16)
    mgemm_k<4><<<dim3(16, 18, 1), blk, 0, stream>>>(sn, qkvT, nullptr, qkv,
                                                    nullptr, nullptr, 384, 1152, 1);

    // 3) fused pair-bias + attention chunks
    fa2_k<<<dim3(32, 32), dim3(128), 0, stream>>>(pair, Wb, qkv, Opart, mlb);

    // 4) combine chunks -> attb
    combine_k<<<dim3(16, 12), blk, 0, stream>>>(Opart, mlb, attb);

    // 5) s1 += att @ Wo (split-K=2, atomic)
    mgemm_k<5><<<dim3(16, 6, 2), blk, 0, stream>>>(attb, WoT, s1, nullptr,
                                                   nullptr, nullptr, 384, 384, 2);

    // 6) LN2 -> hn ; out = s1 + b2
    ln_k<<<dim3(256), blk, 0, stream>>>(s1, g_f, b_f, hn, out, b2);

    // 7) t1 = gelu(hn @ W1 + b1)
    mgemm_k<3><<<dim3(16, 24, 1), blk, 0, stream>>>(hn, W1T, nullptr, t1,
                                                    b1, nullptr, 384, 1536, 1);

    // 8) out += t1 @ W2 (split-K=2, atomic)
    mgemm_k<5><<<dim3(16, 6, 2), blk, 0, stream>>>(t1, W2T, out, nullptr,
                                                   nullptr, nullptr, 1536, 384, 2);
}